// Round 9
// baseline (235.863 us; speedup 1.0000x reference)
//
#include <hip/hip_runtime.h>
#include <cstdint>
#include <cstddef>

// ---------------------------------------------------------------------------
// Mamba2 layer forward (B=4, L=2048, d_model=512, d_inner=1024, d_state=128,
// nheads=1, d_conv=4). SSD formulation: scan as chunked bf16 MFMA GEMMs.
// R5 SSD 609->281; R6 global_load_lds 281->263; R7 XOR-swizzle 263->253;
// R8 fusion/traffic 253->233. R9: LDS-repacked vectorized GEMM epilogues
// (64 scalar 2B stores -> 16B chunks, padded conflict-free LDS) + cumsum
// folded into GEMM1 grid (bn==18). 8 launches.
// ---------------------------------------------------------------------------

typedef __bf16 bf16_t;
typedef __bf16 bf16x8 __attribute__((ext_vector_type(8)));
typedef __bf16 bf16x4 __attribute__((ext_vector_type(4)));
typedef float  f32x4  __attribute__((ext_vector_type(4)));

#define BATCH   4
#define SEQLEN  2048
#define MROWS   8192
#define DMODEL  512
#define DINNER  1024
#define DSTATE  128
#define NZX     2304
#define NCONV   1280
#define CHUNK   128
#define NCHUNK  16
#define NBC     64            // BATCH * NCHUNK

__device__ __forceinline__ float siluf(float x) { return x / (1.f + __expf(-x)); }

// async global->LDS, 16B per lane. LDS dst is wave-uniform base + lane*16.
__device__ __forceinline__ void load_lds16(const bf16_t* g, bf16_t* l)
{
    __builtin_amdgcn_global_load_lds(
        (const __attribute__((address_space(1))) void*)g,
        (__attribute__((address_space(3))) void*)l,
        16, 0, 0);
}

// ---------------------------------------------------------------------------
// GEMM body: C[m,n] = sum_k A[m*lda+k] * B[n*ldb+k]; 128x128 tile, BK=64,
// XOR-swizzled staging; epilogue repacks acc via padded LDS -> 16B stores.
// ---------------------------------------------------------------------------
template <typename OutT>
__device__ __forceinline__ void gemm_body(
    const bf16_t* __restrict__ A, const bf16_t* __restrict__ B,
    OutT* __restrict__ C, int Ntot, int K, int lda, int ldb, int bn, int bm)
{
    __shared__ __align__(16) unsigned char smem[32768];
    bf16_t* As = (bf16_t*)smem;
    bf16_t* Bs = (bf16_t*)(smem + 16384);

    const int tid  = threadIdx.x;
    const int wave = tid >> 6, lane = tid & 63;
    const int lr = lane & 15, q = lane >> 4;
    const int wm = (wave & 1) * 64, wn = (wave >> 1) * 64;

    f32x4 acc[4][4];
    #pragma unroll
    for (int i = 0; i < 4; ++i)
        #pragma unroll
        for (int j = 0; j < 4; ++j)
            acc[i][j] = (f32x4){0.f, 0.f, 0.f, 0.f};

    const int row_a0 = bm * 128, row_b0 = bn * 128;
    const int srow = tid >> 3;
    const int gsw  = (((tid & 7) ^ (srow & 7))) * 8;   // swizzled global chunk
    const int lsl  = (tid & 7) * 8;                    // natural LDS slot

    for (int kt = 0; kt < K; kt += 64) {
        #pragma unroll
        for (int i = 0; i < 4; ++i) {
            int row = srow + i * 32;
            load_lds16(&A[(size_t)(row_a0 + row) * lda + kt + gsw], &As[row * 64 + lsl]);
            load_lds16(&B[(size_t)(row_b0 + row) * ldb + kt + gsw], &Bs[row * 64 + lsl]);
        }
        __syncthreads();
        #pragma unroll
        for (int k0 = 0; k0 < 64; k0 += 32) {
            bf16x8 af[4], bfr[4];
            #pragma unroll
            for (int mi = 0; mi < 4; ++mi) {
                int r = wm + mi * 16 + lr, kc = (k0 >> 3) + q;
                af[mi] = *reinterpret_cast<const bf16x8*>(
                    &As[r * 64 + ((kc ^ (r & 7)) << 3)]);
            }
            #pragma unroll
            for (int ni = 0; ni < 4; ++ni) {
                int r = wn + ni * 16 + lr, kc = (k0 >> 3) + q;
                bfr[ni] = *reinterpret_cast<const bf16x8*>(
                    &Bs[r * 64 + ((kc ^ (r & 7)) << 3)]);
            }
            #pragma unroll
            for (int mi = 0; mi < 4; ++mi)
                #pragma unroll
                for (int ni = 0; ni < 4; ++ni)
                    acc[mi][ni] = __builtin_amdgcn_mfma_f32_16x16x32_bf16(
                        af[mi], bfr[ni], acc[mi][ni], 0, 0, 0);
        }
        __syncthreads();
    }

    // Epilogue: per mi, 32 rows x 128 cols through padded LDS, 16B stores.
    constexpr int EPC = 16 / sizeof(OutT);   // elems per 16B chunk
    constexpr int LD  = 128 + EPC;           // padded row (16B-aligned stride)
    constexpr int CPR = 128 / EPC;           // chunks per row
    OutT* eps = (OutT*)smem;
    #pragma unroll
    for (int mi = 0; mi < 4; ++mi) {
        #pragma unroll
        for (int ni = 0; ni < 4; ++ni)
            #pragma unroll
            for (int ri = 0; ri < 4; ++ri) {
                int lrow = (wave & 1) * 16 + q * 4 + ri;
                int col  = wn + ni * 16 + lr;
                eps[lrow * LD + col] = (OutT)acc[mi][ni][ri];
            }
        __syncthreads();
        #pragma unroll
        for (int pp = 0; pp < (32 * CPR) / 256; ++pp) {
            int ci = pp * 256 + tid;
            int lrow = ci / CPR, ch = ci % CPR;
            int grow = row_a0 + (lrow >> 4) * 64 + mi * 16 + (lrow & 15);
            int gcol = row_b0 + ch * EPC;
            uint4 v = *reinterpret_cast<const uint4*>(&eps[lrow * LD + ch * EPC]);
            *reinterpret_cast<uint4*>(&C[(size_t)grow * Ntot + gcol]) = v;
        }
        __syncthreads();
    }
}

// batched wrapper (GEMM-A, GEMM2)
template <typename OutT>
__global__ __launch_bounds__(256) void gemm_bt_kernel(
    const bf16_t* __restrict__ A, const bf16_t* __restrict__ B,
    OutT* __restrict__ C, int Ntot, int K, int lda, int ldb,
    size_t sA, size_t sB, size_t sC)
{
    gemm_body<OutT>(A + (size_t)blockIdx.z * sA, B + (size_t)blockIdx.z * sB,
                    C + (size_t)blockIdx.z * sC, Ntot, K, lda, ldb,
                    blockIdx.x, blockIdx.y);
}

// ---------------------------------------------------------------------------
// cumsum body (per chunk bc, active threads 0..127): decay scalars.
// ---------------------------------------------------------------------------
__device__ __forceinline__ void cumsum_body(
    const float* __restrict__ dtv, const float* __restrict__ A_log,
    float* __restrict__ sarr, float* __restrict__ Pv,
    float* __restrict__ EdTv, float* __restrict__ chp, int bc)
{
    __shared__ float w0sum, stot;
    int j = threadIdx.x;
    bool active = j < CHUNK;
    int lane = j & 63;
    int r = bc * CHUNK + j;
    float A = -expf(A_log[0]);
    float dt = active ? dtv[r] : 0.f;
    float s = dt;
    #pragma unroll
    for (int m = 1; m <= 32; m <<= 1) {
        float o = __shfl_up(s, m);
        if (lane >= m) s += o;
    }
    if (j == 63) w0sum = s;
    __syncthreads();
    if (j >= 64 && active) s += w0sum;
    if (j == 127) stot = s;
    __syncthreads();
    if (active) {
        float sT = stot;
        sarr[r] = s;
        Pv[r]   = expf(A * s);
        EdTv[r] = expf(A * (sT - s)) * dt;
        if (j == 127) chp[bc] = expf(A * sT);
    }
}

// GEMM1 + fused cumsum (bn==18 column of the grid)
__global__ __launch_bounds__(256) void gemm1_kernel(
    const bf16_t* __restrict__ xb, const bf16_t* __restrict__ winb,
    bf16_t* __restrict__ zx, const float* __restrict__ dtv,
    const float* __restrict__ A_log, float* __restrict__ sarr,
    float* __restrict__ Pv, float* __restrict__ EdTv, float* __restrict__ chp)
{
    if (blockIdx.x < NZX / 128) {
        gemm_body<bf16_t>(xb, winb, zx, NZX, DMODEL, DMODEL, DMODEL,
                          blockIdx.x, blockIdx.y);
    } else {
        cumsum_body(dtv, A_log, sarr, Pv, EdTv, chp, blockIdx.y);
    }
}

// ---------------------------------------------------------------------------
// Y-GEMM: Y[i,p] = sum_{k<256} Mx[i,k] * Dx[p,k]; Dx = [Xt | Stb] per chunk.
// Repacked epilogue (bf16 out).
// ---------------------------------------------------------------------------
__global__ __launch_bounds__(256) void gemm_y_kernel(
    const bf16_t* __restrict__ Mx, const bf16_t* __restrict__ Xt,
    const bf16_t* __restrict__ Stb, bf16_t* __restrict__ yf)
{
    __shared__ __align__(16) unsigned char smem[32768];
    bf16_t* As = (bf16_t*)smem;
    bf16_t* Bs = (bf16_t*)(smem + 16384);

    const int bc = blockIdx.z, bn = blockIdx.x;
    const bf16_t* Ab = Mx + (size_t)bc * 32768;                      // 128x256
    const bf16_t* Xb = Xt  + (size_t)bc * 131072 + (size_t)bn * 128 * 128;
    const bf16_t* Sb = Stb + (size_t)bc * 131072 + (size_t)bn * 128 * 128;
    bf16_t* Cb = yf + (size_t)bc * 131072;

    const int tid  = threadIdx.x;
    const int wave = tid >> 6, lane = tid & 63;
    const int lr = lane & 15, q = lane >> 4;
    const int wm = (wave & 1) * 64, wn = (wave >> 1) * 64;

    f32x4 acc[4][4];
    #pragma unroll
    for (int i = 0; i < 4; ++i)
        #pragma unroll
        for (int j = 0; j < 4; ++j)
            acc[i][j] = (f32x4){0.f, 0.f, 0.f, 0.f};

    const int srow = tid >> 3;
    const int gsw  = (((tid & 7) ^ (srow & 7))) * 8;
    const int lsl  = (tid & 7) * 8;

    for (int kt = 0; kt < 256; kt += 64) {
        const bf16_t* bsrc = (kt < 128) ? (Xb + kt) : (Sb + (kt - 128));
        #pragma unroll
        for (int i = 0; i < 4; ++i) {
            int row = srow + i * 32;
            load_lds16(&Ab[(size_t)row * 256 + kt + gsw], &As[row * 64 + lsl]);
            load_lds16(&bsrc[(size_t)row * 128 + gsw], &Bs[row * 64 + lsl]);
        }
        __syncthreads();
        #pragma unroll
        for (int k0 = 0; k0 < 64; k0 += 32) {
            bf16x8 af[4], bfr[4];
            #pragma unroll
            for (int mi = 0; mi < 4; ++mi) {
                int r = wm + mi * 16 + lr, kc = (k0 >> 3) + q;
                af[mi] = *reinterpret_cast<const bf16x8*>(
                    &As[r * 64 + ((kc ^ (r & 7)) << 3)]);
            }
            #pragma unroll
            for (int ni = 0; ni < 4; ++ni) {
                int r = wn + ni * 16 + lr, kc = (k0 >> 3) + q;
                bfr[ni] = *reinterpret_cast<const bf16x8*>(
                    &Bs[r * 64 + ((kc ^ (r & 7)) << 3)]);
            }
            #pragma unroll
            for (int mi = 0; mi < 4; ++mi)
                #pragma unroll
                for (int ni = 0; ni < 4; ++ni)
                    acc[mi][ni] = __builtin_amdgcn_mfma_f32_16x16x32_bf16(
                        af[mi], bfr[ni], acc[mi][ni], 0, 0, 0);
        }
        __syncthreads();
    }

    constexpr int LD = 136;   // 128 + 8 (16B pad)
    bf16_t* eps = (bf16_t*)smem;
    #pragma unroll
    for (int mi = 0; mi < 4; ++mi) {
        #pragma unroll
        for (int ni = 0; ni < 4; ++ni)
            #pragma unroll
            for (int ri = 0; ri < 4; ++ri) {
                int lrow = (wave & 1) * 16 + q * 4 + ri;
                int col  = wn + ni * 16 + lr;
                eps[lrow * LD + col] = (bf16_t)acc[mi][ni][ri];
            }
        __syncthreads();
        #pragma unroll
        for (int pp = 0; pp < 2; ++pp) {
            int ci = pp * 256 + tid;
            int lrow = ci >> 4, ch = ci & 15;
            int grow = (lrow >> 4) * 64 + mi * 16 + (lrow & 15);
            int gcol = bn * 128 + ch * 8;
            uint4 v = *reinterpret_cast<const uint4*>(&eps[lrow * LD + ch * 8]);
            *reinterpret_cast<uint4*>(&Cb[(size_t)grow * 1024 + gcol]) = v;
        }
        __syncthreads();
    }
}

// ---------------------------------------------------------------------------
// Fused: dt column (one wave per row, fp32 exact) + x->bf16 cast  [blocks
// 0..2047], then W_in/W_out -> bf16 casts [blocks 2048..].
// ---------------------------------------------------------------------------
__global__ __launch_bounds__(256) void dtcast_kernel(
    const float* __restrict__ x, const float* __restrict__ W_in,
    const float* __restrict__ dt_bias, const float* __restrict__ W_out,
    float* __restrict__ dtv, bf16_t* __restrict__ xb,
    bf16_t* __restrict__ winb, bf16_t* __restrict__ woutb)
{
    int bid = blockIdx.x;
    if (bid < MROWS / 4) {
        int wave = threadIdx.x >> 6, lane = threadIdx.x & 63;
        int r = bid * 4 + wave;
        const float* xr = x + (size_t)r * DMODEL + lane * 8;
        const float* wr = W_in + (size_t)NZX * DMODEL + lane * 8;
        float4 a0 = *reinterpret_cast<const float4*>(xr);
        float4 a1 = *reinterpret_cast<const float4*>(xr + 4);
        float4 b0 = *reinterpret_cast<const float4*>(wr);
        float4 b1 = *reinterpret_cast<const float4*>(wr + 4);

        bf16x8 xo;
        xo[0] = (bf16_t)a0.x; xo[1] = (bf16_t)a0.y; xo[2] = (bf16_t)a0.z; xo[3] = (bf16_t)a0.w;
        xo[4] = (bf16_t)a1.x; xo[5] = (bf16_t)a1.y; xo[6] = (bf16_t)a1.z; xo[7] = (bf16_t)a1.w;
        *reinterpret_cast<bf16x8*>(xb + (size_t)r * DMODEL + lane * 8) = xo;

        float s = a0.x * b0.x + a0.y * b0.y + a0.z * b0.z + a0.w * b0.w
                + a1.x * b1.x + a1.y * b1.y + a1.z * b1.z + a1.w * b1.w;
        #pragma unroll
        for (int m = 32; m >= 1; m >>= 1) s += __shfl_xor(s, m);
        if (lane == 0) {
            float t  = s + dt_bias[0];
            dtv[r] = (t > 20.f) ? t : log1pf(expf(t));
        }
        return;
    }
    int i = (bid - MROWS / 4) * 256 + threadIdx.x;
    const int n4a = 2305 * DMODEL / 4, n4b = DMODEL * DINNER / 4;
    const float* src; bf16_t* dst; int j;
    if (i < n4a)            { src = W_in;  dst = winb;  j = i; }
    else if (i < n4a + n4b) { src = W_out; dst = woutb; j = i - n4a; }
    else return;
    float4 v = reinterpret_cast<const float4*>(src)[j];
    bf16x4 o;
    o[0] = (bf16_t)v.x; o[1] = (bf16_t)v.y; o[2] = (bf16_t)v.z; o[3] = (bf16_t)v.w;
    reinterpret_cast<bf16x4*>(dst)[j] = o;
}

// ---------------------------------------------------------------------------
// Fused conv + transpose per (col-group cg 0..9, chunk bc).
// ---------------------------------------------------------------------------
__global__ __launch_bounds__(256) void conv_tr_kernel(
    const bf16_t* __restrict__ zx, const float* __restrict__ cw,
    const float* __restrict__ cb, const float* __restrict__ EdTv,
    bf16_t* __restrict__ xbc, bf16_t* __restrict__ Xt, bf16_t* __restrict__ Bwt)
{
    constexpr int TS = 132;
    __shared__ bf16_t tile[128 * TS];
    __shared__ float cwS[128 * 4];
    __shared__ float cbS[128];

    int cg = blockIdx.x, bc = blockIdx.y;
    int tid = threadIdx.x;
    int c0 = cg * 128;

    if (tid < 128) {
        float4 w = *reinterpret_cast<const float4*>(cw + (size_t)(c0 + tid) * 4);
        *reinterpret_cast<float4*>(&cwS[tid * 4]) = w;
        cbS[tid] = cb[c0 + tid];
    }
    __syncthreads();

    int lrow = tid >> 4, lc8 = (tid & 15) * 8;
    int g0 = bc * 128;

    #pragma unroll
    for (int pass = 0; pass < 8; ++pass) {
        int row = pass * 16 + lrow;
        int g = g0 + row;
        int l = g & (SEQLEN - 1);
        float acc[8];
        #pragma unroll
        for (int m = 0; m < 8; ++m) acc[m] = cbS[lc8 + m];
        #pragma unroll
        for (int k = 0; k < 4; ++k) {
            if (l + k >= 3) {
                bf16x8 v = *reinterpret_cast<const bf16x8*>(
                    zx + (size_t)(g + k - 3) * NZX + DINNER + c0 + lc8);
                #pragma unroll
                for (int m = 0; m < 8; ++m)
                    acc[m] += cwS[(lc8 + m) * 4 + k] * (float)v[m];
            }
        }
        bf16x8 o;
        #pragma unroll
        for (int m = 0; m < 8; ++m) o[m] = (bf16_t)siluf(acc[m]);
        *reinterpret_cast<bf16x8*>(xbc + (size_t)g * NCONV + c0 + lc8) = o;
        if (cg < 9) {
            bf16x4 lo, hi;
            #pragma unroll
            for (int m = 0; m < 4; ++m) { lo[m] = o[m]; hi[m] = o[m + 4]; }
            *reinterpret_cast<bf16x4*>(&tile[row * TS + lc8]) = lo;
            *reinterpret_cast<bf16x4*>(&tile[row * TS + lc8 + 4]) = hi;
        }
    }
    if (cg == 9) return;
    __syncthreads();

    const bool isB = (cg == 8);
    int jo = (tid >> 4) * 8;
    float sc[8];
    #pragma unroll
    for (int m = 0; m < 8; ++m)
        sc[m] = isB ? EdTv[bc * 128 + jo + m] : 1.f;

    #pragma unroll
    for (int pass = 0; pass < 8; ++pass) {
        int oc = pass * 16 + (tid & 15);
        bf16x8 o;
        #pragma unroll
        for (int m = 0; m < 8; ++m)
            o[m] = (bf16_t)((float)tile[(jo + m) * TS + oc] * sc[m]);
        bf16_t* dst = isB
            ? (Bwt + (size_t)bc * 16384 + (size_t)oc * 128 + jo)
            : (Xt + (size_t)bc * 131072 + ((size_t)c0 + oc) * 128 + jo);
        *reinterpret_cast<bf16x8*>(dst) = o;
    }
}

// ---------------------------------------------------------------------------
// Sequential chunk combine: S_init(c) = chp(c-1)*S_init(c-1) + S_loc(c-1)
// ---------------------------------------------------------------------------
__global__ __launch_bounds__(256) void scan_combine_kernel(
    const bf16_t* __restrict__ cstate, const float* __restrict__ chp,
    bf16_t* __restrict__ Stb)
{
    int idx = blockIdx.x * 256 + threadIdx.x;   // B * 131072
    int b   = idx >> 17;
    int np  = idx & 131071;
    float v = 0.f;
    for (int c = 0; c < NCHUNK; ++c) {
        size_t off = ((size_t)(b * NCHUNK + c) << 17) + np;
        Stb[off] = (bf16_t)v;
        float tmp = (float)cstate[off];
        v = chp[b * NCHUNK + c] * v + tmp;
    }
}

// ---------------------------------------------------------------------------
// mbuild (fused GEMM-G): per chunk, stage C,B tiles (swizzled), MFMA
// G = C@B^T, then write Mx = [mask-decay(G) | P*C] bf16.
// ---------------------------------------------------------------------------
__global__ __launch_bounds__(256) void mbuild_kernel(
    const float* __restrict__ sarr, const float* __restrict__ dtv,
    const float* __restrict__ Pv, const float* __restrict__ A_log,
    const bf16_t* __restrict__ xbc, bf16_t* __restrict__ Mx)
{
    __shared__ __align__(16) bf16_t Cs[128 * 128];
    __shared__ __align__(16) bf16_t Bs2[128 * 128];
    __shared__ float sj[CHUNK], dj[CHUNK], pj[CHUNK];

    int bc = blockIdx.x, tid = threadIdx.x;
    if (tid < CHUNK) {
        sj[tid] = sarr[bc * CHUNK + tid];
        dj[tid] = dtv[bc * CHUNK + tid];
        pj[tid] = Pv[bc * CHUNK + tid];
    }
    int rowbase = bc * 128;
    int srow = tid >> 4;
    int gsw  = (((tid & 15) ^ (srow & 7))) * 8;
    int lsl  = (tid & 15) * 8;
    #pragma unroll
    for (int i = 0; i < 8; ++i) {
        int row = srow + i * 16;
        load_lds16(&xbc[(size_t)(rowbase + row) * NCONV + 1152 + gsw], &Cs[row * 128 + lsl]);
        load_lds16(&xbc[(size_t)(rowbase + row) * NCONV + 1024 + gsw], &Bs2[row * 128 + lsl]);
    }
    __syncthreads();

    const int wave = tid >> 6, lane = tid & 63;
    const int lr = lane & 15, q = lane >> 4;
    const int wm = (wave & 1) * 64, wn = (wave >> 1) * 64;

    f32x4 acc[4][4];
    #pragma unroll
    for (int i = 0; i < 4; ++i)
        #pragma unroll
        for (int j = 0; j < 4; ++j)
            acc[i][j] = (f32x4){0.f, 0.f, 0.f, 0.f};

    #pragma unroll
    for (int k0 = 0; k0 < 128; k0 += 32) {
        bf16x8 af[4], bfr[4];
        #pragma unroll
        for (int mi = 0; mi < 4; ++mi) {
            int r = wm + mi * 16 + lr, kc = (k0 >> 3) + q;
            af[mi] = *reinterpret_cast<const bf16x8*>(
                &Cs[r * 128 + ((kc ^ (r & 7)) << 3)]);
        }
        #pragma unroll
        for (int ni = 0; ni < 4; ++ni) {
            int r = wn + ni * 16 + lr, kc = (k0 >> 3) + q;
            bfr[ni] = *reinterpret_cast<const bf16x8*>(
                &Bs2[r * 128 + ((kc ^ (r & 7)) << 3)]);
        }
        #pragma unroll
        for (int mi = 0; mi < 4; ++mi)
            #pragma unroll
            for (int ni = 0; ni < 4; ++ni)
                acc[mi][ni] = __builtin_amdgcn_mfma_f32_16x16x32_bf16(
                    af[mi], bfr[ni], acc[mi][ni], 0, 0, 0);
    }

    float A = -expf(A_log[0]);
    bf16_t* MxB = Mx + (size_t)bc * 32768;
    #pragma unroll
    for (int mi = 0; mi < 4; ++mi)
        #pragma unroll
        for (int ni = 0; ni < 4; ++ni)
            #pragma unroll
            for (int ri = 0; ri < 4; ++ri) {
                int row = wm + mi * 16 + q * 4 + ri;
                int col = wn + ni * 16 + lr;
                float val = 0.f;
                if (col <= row)
                    val = acc[mi][ni][ri] * expf(A * (sj[row] - sj[col])) * dj[col];
                MxB[(size_t)row * 256 + col] = (bf16_t)val;
            }

    // Cw half from LDS (undo swizzle): Mx[row][128+n] = P_row * C[row][n]
    int rr = tid >> 1, cb2 = (tid & 1) * 64;
    float Pi = pj[rr];
    #pragma unroll
    for (int m0 = 0; m0 < 64; m0 += 8) {
        int kc = (cb2 + m0) >> 3;
        bf16x8 cv = *reinterpret_cast<const bf16x8*>(
            &Cs[rr * 128 + ((kc ^ (rr & 7)) << 3)]);
        bf16x8 o;
        #pragma unroll
        for (int m = 0; m < 8; ++m) o[m] = (bf16_t)((float)cv[m] * Pi);
        *reinterpret_cast<bf16x8*>(&MxB[(size_t)rr * 256 + 128 + cb2 + m0]) = o;
    }
}

// ---------------------------------------------------------------------------
// Gate + RMSNorm (+ fused rnn passthrough in tail blocks)
// ---------------------------------------------------------------------------
__global__ __launch_bounds__(256) void gate_norm_kernel(
    const bf16_t* __restrict__ yf, const bf16_t* __restrict__ zx,
    const bf16_t* __restrict__ xbc, const float* __restrict__ Dp,
    const float* __restrict__ norm_w, bf16_t* __restrict__ yb,
    const float* __restrict__ rnn, float* __restrict__ outTail)
{
    __shared__ float red[4];
    int r = blockIdx.x, tid = threadIdx.x;
    if (r >= MROWS) {
        int i = (r - MROWS) * 256 + tid;
        if (i < BATCH * DMODEL) outTail[i] = rnn[i];
        return;
    }
    int p = tid * 4;
    float D0 = Dp[0];
    bf16x4 yv = *reinterpret_cast<const bf16x4*>(yf + (size_t)r * DINNER + p);
    bf16x4 zv = *reinterpret_cast<const bf16x4*>(zx + (size_t)r * NZX + p);
    bf16x4 xv = *reinterpret_cast<const bf16x4*>(xbc + (size_t)r * NCONV + p);
    float g0 = ((float)yv[0] + D0 * (float)xv[0]) * siluf((float)zv[0]);
    float g1 = ((float)yv[1] + D0 * (float)xv[1]) * siluf((float)zv[1]);
    float g2 = ((float)yv[2] + D0 * (float)xv[2]) * siluf((float)zv[2]);
    float g3 = ((float)yv[3] + D0 * (float)xv[3]) * siluf((float)zv[3]);
    float ss = g0 * g0 + g1 * g1 + g2 * g2 + g3 * g3;
    #pragma unroll
    for (int m = 32; m >= 1; m >>= 1) ss += __shfl_xor(ss, m);
    if ((tid & 63) == 0) red[tid >> 6] = ss;
    __syncthreads();
    float tot = red[0] + red[1] + red[2] + red[3];
    float scale = rsqrtf(tot * (1.f / 1024.f) + 1e-5f);
    float4 nw = *reinterpret_cast<const float4*>(norm_w + p);
    bf16x4 o;
    o[0] = (bf16_t)(g0 * scale * nw.x);
    o[1] = (bf16_t)(g1 * scale * nw.y);
    o[2] = (bf16_t)(g2 * scale * nw.z);
    o[3] = (bf16_t)(g3 * scale * nw.w);
    *reinterpret_cast<bf16x4*>(yb + (size_t)r * DINNER + p) = o;
}

// ---------------------------------------------------------------------------
extern "C" void kernel_launch(void* const* d_in, const int* in_sizes, int n_in,
                              void* d_out, int out_size, void* d_ws, size_t ws_size,
                              hipStream_t stream)
{
    const float* x        = (const float*)d_in[0];
    const float* rnn      = (const float*)d_in[1];
    const float* W_in     = (const float*)d_in[2];
    const float* conv_w   = (const float*)d_in[3];
    const float* conv_b   = (const float*)d_in[4];
    const float* dt_bias  = (const float*)d_in[5];
    const float* A_log    = (const float*)d_in[6];
    const float* Dp       = (const float*)d_in[7];
    const float* norm_w   = (const float*)d_in[8];
    const float* W_out    = (const float*)d_in[9];
    float* out = (float*)d_out;

    // workspace carve
    char* ws = (char*)d_ws;
    bf16_t* xb     = (bf16_t*)(ws + 0);                       //  8,388,608 (dead after GEMM1)
    bf16_t* Mx     = (bf16_t*)(ws + 4194304);                 //  4,194,304 (alias over xb tail)
    bf16_t* winb   = (bf16_t*)(ws + 8388608);                 //  2,360,320
    bf16_t* woutb  = (bf16_t*)(ws + 10748928);                //  1,048,576
    bf16_t* zx     = (bf16_t*)(ws + 11797504);                // 37,748,736
    float*  dtv    = (float*) (ws + 49546240);                //     32,768
    float*  sarr   = (float*) (ws + 49579008);                //     32,768
    float*  Pv     = (float*) (ws + 49611776);                //     32,768
    float*  EdTv   = (float*) (ws + 49644544);                //     32,768
    float*  chp    = (float*) (ws + 49677312);                //        256
    bf16_t* xbcb   = (bf16_t*)(ws + 49677568);                // 20,971,520
    bf16_t* Xt     = (bf16_t*)(ws + 70649088);                // 16,777,216
    bf16_t* Bwt    = (bf16_t*)(ws + 87426304);                //  2,097,152
    bf16_t* cstate = (bf16_t*)(ws + 89523456);                // 16,777,216 (S_loc bf16)
    bf16_t* yf     = (bf16_t*)(ws + 89523456);                // alias over dead cstate
    bf16_t* Stb    = (bf16_t*)(ws + 106300672);               // 16,777,216
    bf16_t* yb     = (bf16_t*)(ws + 123077888);               // 16,777,216
    // end: 139,855,104 bytes

    // 1) dt (fp32) + x cast + weight casts (one kernel, block-range split)
    {
        const int n4a = 2305 * DMODEL / 4, n4b = DMODEL * DINNER / 4;
        int grid = MROWS / 4 + (n4a + n4b + 255) / 256;
        dtcast_kernel<<<grid, 256, 0, stream>>>(
            x, W_in, dt_bias, W_out, dtv, xb, winb, woutb);
    }

    // 2) GEMM1 (+ fused cumsum in bn==18 blocks)
    gemm1_kernel<<<dim3(NZX / 128 + 1, MROWS / 128, 1), 256, 0, stream>>>(
        xb, winb, zx, dtv, A_log, sarr, Pv, EdTv, chp);

    // 3) fused conv + transpose (writes xbcb, Xt, Bwt)
    conv_tr_kernel<<<dim3(10, NBC), 256, 0, stream>>>(
        zx, conv_w, conv_b, EdTv, xbcb, Xt, Bwt);

    // 4) GEMM-A: S_loc[p,n] = Xt @ Bwt^T  (per chunk, bf16 out)
    gemm_bt_kernel<bf16_t><<<dim3(1, 8, NBC), 256, 0, stream>>>(
        Xt, Bwt, cstate, DSTATE, CHUNK, CHUNK, CHUNK,
        131072, 16384, 131072);

    // 5) combine -> Stb bf16 (S_init per chunk, [p,n])
    scan_combine_kernel<<<BATCH * 131072 / 256, 256, 0, stream>>>(cstate, chp, Stb);

    // 6) mbuild (fused G-GEMM): Mx = [decay-masked C@B^T | P*C]
    mbuild_kernel<<<NBC, 256, 0, stream>>>(sarr, dtv, Pv, A_log, xbcb, Mx);

    // 7) GEMM-Y: yf[i,p] = Mx @ [Xt;Stb]^T  (bf16 out)
    gemm_y_kernel<<<dim3(8, 1, NBC), 256, 0, stream>>>(Mx, Xt, Stb, yf);

    // 8) gate + RMSNorm -> yb bf16 (+ rnn passthrough tail blocks)
    gate_norm_kernel<<<MROWS + 8, 256, 0, stream>>>(
        yf, zx, xbcb, Dp, norm_w, yb, rnn, out + (size_t)MROWS * DMODEL);

    // 9) GEMM2: out[8192,512] = yb @ woutb^T (f32, into d_out)
    gemm_bt_kernel<float><<<dim3(DMODEL / 128, MROWS / 128, 1), 256, 0, stream>>>(
        yb, woutb, out, DMODEL, DINNER, DINNER, DINNER, 0, 0, 0);
}

// Round 10
// 234.190 us; speedup vs baseline: 1.0071x; 1.0071x over previous
//
#include <hip/hip_runtime.h>
#include <cstdint>
#include <cstddef>

// ---------------------------------------------------------------------------
// Mamba2 layer forward (B=4, L=2048, d_model=512, d_inner=1024, d_state=128,
// nheads=1, d_conv=4). SSD formulation: scan as chunked bf16 MFMA GEMMs.
// R5 SSD 609->281; R6 global_load_lds 281->263; R7 XOR-swizzle 263->253;
// R8 fusion/traffic 253->233; R9 epilogue repack REGRESSED (+8 barriers,
// 236) -> reverted. R10: direct-store epilogues + XCD-aware grid swizzle
// for GEMM1/GEMM2 (per-XCD bm-band -> A-tile fits 4MB L2; GEMM1 FETCH was
// 60MB vs 10.8MB unique = 8x XCD overfetch).
// ---------------------------------------------------------------------------

typedef __bf16 bf16_t;
typedef __bf16 bf16x8 __attribute__((ext_vector_type(8)));
typedef __bf16 bf16x4 __attribute__((ext_vector_type(4)));
typedef float  f32x4  __attribute__((ext_vector_type(4)));

#define BATCH   4
#define SEQLEN  2048
#define MROWS   8192
#define DMODEL  512
#define DINNER  1024
#define DSTATE  128
#define NZX     2304
#define NCONV   1280
#define CHUNK   128
#define NCHUNK  16
#define NBC     64            // BATCH * NCHUNK

__device__ __forceinline__ float siluf(float x) { return x / (1.f + __expf(-x)); }

// async global->LDS, 16B per lane. LDS dst is wave-uniform base + lane*16.
__device__ __forceinline__ void load_lds16(const bf16_t* g, bf16_t* l)
{
    __builtin_amdgcn_global_load_lds(
        (const __attribute__((address_space(1))) void*)g,
        (__attribute__((address_space(3))) void*)l,
        16, 0, 0);
}

// ---------------------------------------------------------------------------
// GEMM body: C[m,n] = sum_k A[m*lda+k] * B[n*ldb+k]; 128x128 tile, BK=64,
// XOR-swizzled global_load_lds staging; direct-store epilogue (R8-proven).
// ---------------------------------------------------------------------------
template <typename OutT>
__device__ __forceinline__ void gemm_body(
    const bf16_t* __restrict__ A, const bf16_t* __restrict__ B,
    OutT* __restrict__ C, int Ntot, int K, int lda, int ldb, int bn, int bm)
{
    __shared__ __align__(16) bf16_t As[128 * 64];
    __shared__ __align__(16) bf16_t Bs[128 * 64];

    const int tid  = threadIdx.x;
    const int wave = tid >> 6, lane = tid & 63;
    const int lr = lane & 15, q = lane >> 4;
    const int wm = (wave & 1) * 64, wn = (wave >> 1) * 64;

    f32x4 acc[4][4];
    #pragma unroll
    for (int i = 0; i < 4; ++i)
        #pragma unroll
        for (int j = 0; j < 4; ++j)
            acc[i][j] = (f32x4){0.f, 0.f, 0.f, 0.f};

    const int row_a0 = bm * 128, row_b0 = bn * 128;
    const int srow = tid >> 3;
    const int gsw  = (((tid & 7) ^ (srow & 7))) * 8;   // swizzled global chunk
    const int lsl  = (tid & 7) * 8;                    // natural LDS slot

    for (int kt = 0; kt < K; kt += 64) {
        #pragma unroll
        for (int i = 0; i < 4; ++i) {
            int row = srow + i * 32;
            load_lds16(&A[(size_t)(row_a0 + row) * lda + kt + gsw], &As[row * 64 + lsl]);
            load_lds16(&B[(size_t)(row_b0 + row) * ldb + kt + gsw], &Bs[row * 64 + lsl]);
        }
        __syncthreads();
        #pragma unroll
        for (int k0 = 0; k0 < 64; k0 += 32) {
            bf16x8 af[4], bfr[4];
            #pragma unroll
            for (int mi = 0; mi < 4; ++mi) {
                int r = wm + mi * 16 + lr, kc = (k0 >> 3) + q;
                af[mi] = *reinterpret_cast<const bf16x8*>(
                    &As[r * 64 + ((kc ^ (r & 7)) << 3)]);
            }
            #pragma unroll
            for (int ni = 0; ni < 4; ++ni) {
                int r = wn + ni * 16 + lr, kc = (k0 >> 3) + q;
                bfr[ni] = *reinterpret_cast<const bf16x8*>(
                    &Bs[r * 64 + ((kc ^ (r & 7)) << 3)]);
            }
            #pragma unroll
            for (int mi = 0; mi < 4; ++mi)
                #pragma unroll
                for (int ni = 0; ni < 4; ++ni)
                    acc[mi][ni] = __builtin_amdgcn_mfma_f32_16x16x32_bf16(
                        af[mi], bfr[ni], acc[mi][ni], 0, 0, 0);
        }
        __syncthreads();
    }

    #pragma unroll
    for (int mi = 0; mi < 4; ++mi)
        #pragma unroll
        for (int ni = 0; ni < 4; ++ni)
            #pragma unroll
            for (int ri = 0; ri < 4; ++ri) {
                int row = row_a0 + wm + mi * 16 + q * 4 + ri;
                int col = row_b0 + wn + ni * 16 + lr;
                C[(size_t)row * Ntot + col] = (OutT)acc[mi][ni][ri];
            }
}

// batched wrapper (GEMM-A)
template <typename OutT>
__global__ __launch_bounds__(256) void gemm_bt_kernel(
    const bf16_t* __restrict__ A, const bf16_t* __restrict__ B,
    OutT* __restrict__ C, int Ntot, int K, int lda, int ldb,
    size_t sA, size_t sB, size_t sC)
{
    gemm_body<OutT>(A + (size_t)blockIdx.z * sA, B + (size_t)blockIdx.z * sB,
                    C + (size_t)blockIdx.z * sC, Ntot, K, lda, ldb,
                    blockIdx.x, blockIdx.y);
}

// ---------------------------------------------------------------------------
// cumsum body (per chunk bc, active threads 0..127): decay scalars.
// ---------------------------------------------------------------------------
__device__ __forceinline__ void cumsum_body(
    const float* __restrict__ dtv, const float* __restrict__ A_log,
    float* __restrict__ sarr, float* __restrict__ Pv,
    float* __restrict__ EdTv, float* __restrict__ chp, int bc)
{
    __shared__ float w0sum, stot;
    int j = threadIdx.x;
    bool active = j < CHUNK;
    int lane = j & 63;
    int r = bc * CHUNK + j;
    float A = -expf(A_log[0]);
    float dt = active ? dtv[r] : 0.f;
    float s = dt;
    #pragma unroll
    for (int m = 1; m <= 32; m <<= 1) {
        float o = __shfl_up(s, m);
        if (lane >= m) s += o;
    }
    if (j == 63) w0sum = s;
    __syncthreads();
    if (j >= 64 && active) s += w0sum;
    if (j == 127) stot = s;
    __syncthreads();
    if (active) {
        float sT = stot;
        sarr[r] = s;
        Pv[r]   = expf(A * s);
        EdTv[r] = expf(A * (sT - s)) * dt;
        if (j == 127) chp[bc] = expf(A * sT);
    }
}

// GEMM1 (XCD-aware swizzle: per-XCD bm band) + fused cumsum (tail blocks)
__global__ __launch_bounds__(256) void gemm1_kernel(
    const bf16_t* __restrict__ xb, const bf16_t* __restrict__ winb,
    bf16_t* __restrict__ zx, const float* __restrict__ dtv,
    const float* __restrict__ A_log, float* __restrict__ sarr,
    float* __restrict__ Pv, float* __restrict__ EdTv, float* __restrict__ chp)
{
    int linear = blockIdx.x;
    if (linear < (NZX / 128) * (MROWS / 128)) {     // 18*64 = 1152
        int xcd = linear & 7, j = linear >> 3;      // j in [0,144)
        int bm = xcd * 8 + (j & 7);                 // 8-row bm band per XCD
        int bn = j >> 3;                            // [0,18)
        gemm_body<bf16_t>(xb, winb, zx, NZX, DMODEL, DMODEL, DMODEL, bn, bm);
    } else {
        cumsum_body(dtv, A_log, sarr, Pv, EdTv, chp, linear - 1152);
    }
}

// GEMM2 with the same XCD-aware swizzle (256 blocks: 4 bn x 64 bm)
__global__ __launch_bounds__(256) void gemm2_kernel(
    const bf16_t* __restrict__ yb, const bf16_t* __restrict__ woutb,
    float* __restrict__ out)
{
    int linear = blockIdx.x;                        // [0,256)
    int xcd = linear & 7, j = linear >> 3;          // j in [0,32)
    int bm = xcd * 8 + (j & 7);
    int bn = j >> 3;                                // [0,4)
    gemm_body<float>(yb, woutb, out, DMODEL, DINNER, DINNER, DINNER, bn, bm);
}

// ---------------------------------------------------------------------------
// Y-GEMM: Y[i,p] = sum_{k<256} Mx[i,k] * Dx[p,k]; Dx = [Xt | Stb] per chunk.
// Direct-store epilogue (bf16 out).
// ---------------------------------------------------------------------------
__global__ __launch_bounds__(256) void gemm_y_kernel(
    const bf16_t* __restrict__ Mx, const bf16_t* __restrict__ Xt,
    const bf16_t* __restrict__ Stb, bf16_t* __restrict__ yf)
{
    __shared__ __align__(16) bf16_t As[128 * 64];
    __shared__ __align__(16) bf16_t Bs[128 * 64];

    const int bc = blockIdx.z, bn = blockIdx.x;
    const bf16_t* Ab = Mx + (size_t)bc * 32768;                      // 128x256
    const bf16_t* Xb = Xt  + (size_t)bc * 131072 + (size_t)bn * 128 * 128;
    const bf16_t* Sb = Stb + (size_t)bc * 131072 + (size_t)bn * 128 * 128;
    bf16_t* Cb = yf + (size_t)bc * 131072;

    const int tid  = threadIdx.x;
    const int wave = tid >> 6, lane = tid & 63;
    const int lr = lane & 15, q = lane >> 4;
    const int wm = (wave & 1) * 64, wn = (wave >> 1) * 64;

    f32x4 acc[4][4];
    #pragma unroll
    for (int i = 0; i < 4; ++i)
        #pragma unroll
        for (int j = 0; j < 4; ++j)
            acc[i][j] = (f32x4){0.f, 0.f, 0.f, 0.f};

    const int srow = tid >> 3;
    const int gsw  = (((tid & 7) ^ (srow & 7))) * 8;
    const int lsl  = (tid & 7) * 8;

    for (int kt = 0; kt < 256; kt += 64) {
        const bf16_t* bsrc = (kt < 128) ? (Xb + kt) : (Sb + (kt - 128));
        #pragma unroll
        for (int i = 0; i < 4; ++i) {
            int row = srow + i * 32;
            load_lds16(&Ab[(size_t)row * 256 + kt + gsw], &As[row * 64 + lsl]);
            load_lds16(&bsrc[(size_t)row * 128 + gsw], &Bs[row * 64 + lsl]);
        }
        __syncthreads();
        #pragma unroll
        for (int k0 = 0; k0 < 64; k0 += 32) {
            bf16x8 af[4], bfr[4];
            #pragma unroll
            for (int mi = 0; mi < 4; ++mi) {
                int r = wm + mi * 16 + lr, kc = (k0 >> 3) + q;
                af[mi] = *reinterpret_cast<const bf16x8*>(
                    &As[r * 64 + ((kc ^ (r & 7)) << 3)]);
            }
            #pragma unroll
            for (int ni = 0; ni < 4; ++ni) {
                int r = wn + ni * 16 + lr, kc = (k0 >> 3) + q;
                bfr[ni] = *reinterpret_cast<const bf16x8*>(
                    &Bs[r * 64 + ((kc ^ (r & 7)) << 3)]);
            }
            #pragma unroll
            for (int mi = 0; mi < 4; ++mi)
                #pragma unroll
                for (int ni = 0; ni < 4; ++ni)
                    acc[mi][ni] = __builtin_amdgcn_mfma_f32_16x16x32_bf16(
                        af[mi], bfr[ni], acc[mi][ni], 0, 0, 0);
        }
        __syncthreads();
    }

    #pragma unroll
    for (int mi = 0; mi < 4; ++mi)
        #pragma unroll
        for (int ni = 0; ni < 4; ++ni)
            #pragma unroll
            for (int ri = 0; ri < 4; ++ri) {
                int row = wm + mi * 16 + q * 4 + ri;
                int col = bn * 128 + wn + ni * 16 + lr;
                Cb[(size_t)row * 1024 + col] = (bf16_t)acc[mi][ni][ri];
            }
}

// ---------------------------------------------------------------------------
// Fused: dt column (one wave per row, fp32 exact) + x->bf16 cast  [blocks
// 0..2047], then W_in/W_out -> bf16 casts [blocks 2048..].
// ---------------------------------------------------------------------------
__global__ __launch_bounds__(256) void dtcast_kernel(
    const float* __restrict__ x, const float* __restrict__ W_in,
    const float* __restrict__ dt_bias, const float* __restrict__ W_out,
    float* __restrict__ dtv, bf16_t* __restrict__ xb,
    bf16_t* __restrict__ winb, bf16_t* __restrict__ woutb)
{
    int bid = blockIdx.x;
    if (bid < MROWS / 4) {
        int wave = threadIdx.x >> 6, lane = threadIdx.x & 63;
        int r = bid * 4 + wave;
        const float* xr = x + (size_t)r * DMODEL + lane * 8;
        const float* wr = W_in + (size_t)NZX * DMODEL + lane * 8;
        float4 a0 = *reinterpret_cast<const float4*>(xr);
        float4 a1 = *reinterpret_cast<const float4*>(xr + 4);
        float4 b0 = *reinterpret_cast<const float4*>(wr);
        float4 b1 = *reinterpret_cast<const float4*>(wr + 4);

        bf16x8 xo;
        xo[0] = (bf16_t)a0.x; xo[1] = (bf16_t)a0.y; xo[2] = (bf16_t)a0.z; xo[3] = (bf16_t)a0.w;
        xo[4] = (bf16_t)a1.x; xo[5] = (bf16_t)a1.y; xo[6] = (bf16_t)a1.z; xo[7] = (bf16_t)a1.w;
        *reinterpret_cast<bf16x8*>(xb + (size_t)r * DMODEL + lane * 8) = xo;

        float s = a0.x * b0.x + a0.y * b0.y + a0.z * b0.z + a0.w * b0.w
                + a1.x * b1.x + a1.y * b1.y + a1.z * b1.z + a1.w * b1.w;
        #pragma unroll
        for (int m = 32; m >= 1; m >>= 1) s += __shfl_xor(s, m);
        if (lane == 0) {
            float t  = s + dt_bias[0];
            dtv[r] = (t > 20.f) ? t : log1pf(expf(t));
        }
        return;
    }
    int i = (bid - MROWS / 4) * 256 + threadIdx.x;
    const int n4a = 2305 * DMODEL / 4, n4b = DMODEL * DINNER / 4;
    const float* src; bf16_t* dst; int j;
    if (i < n4a)            { src = W_in;  dst = winb;  j = i; }
    else if (i < n4a + n4b) { src = W_out; dst = woutb; j = i - n4a; }
    else return;
    float4 v = reinterpret_cast<const float4*>(src)[j];
    bf16x4 o;
    o[0] = (bf16_t)v.x; o[1] = (bf16_t)v.y; o[2] = (bf16_t)v.z; o[3] = (bf16_t)v.w;
    reinterpret_cast<bf16x4*>(dst)[j] = o;
}

// ---------------------------------------------------------------------------
// Fused conv + transpose per (col-group cg 0..9, chunk bc).
// ---------------------------------------------------------------------------
__global__ __launch_bounds__(256) void conv_tr_kernel(
    const bf16_t* __restrict__ zx, const float* __restrict__ cw,
    const float* __restrict__ cb, const float* __restrict__ EdTv,
    bf16_t* __restrict__ xbc, bf16_t* __restrict__ Xt, bf16_t* __restrict__ Bwt)
{
    constexpr int TS = 132;
    __shared__ bf16_t tile[128 * TS];
    __shared__ float cwS[128 * 4];
    __shared__ float cbS[128];

    int cg = blockIdx.x, bc = blockIdx.y;
    int tid = threadIdx.x;
    int c0 = cg * 128;

    if (tid < 128) {
        float4 w = *reinterpret_cast<const float4*>(cw + (size_t)(c0 + tid) * 4);
        *reinterpret_cast<float4*>(&cwS[tid * 4]) = w;
        cbS[tid] = cb[c0 + tid];
    }
    __syncthreads();

    int lrow = tid >> 4, lc8 = (tid & 15) * 8;
    int g0 = bc * 128;

    #pragma unroll
    for (int pass = 0; pass < 8; ++pass) {
        int row = pass * 16 + lrow;
        int g = g0 + row;
        int l = g & (SEQLEN - 1);
        float acc[8];
        #pragma unroll
        for (int m = 0; m < 8; ++m) acc[m] = cbS[lc8 + m];
        #pragma unroll
        for (int k = 0; k < 4; ++k) {
            if (l + k >= 3) {
                bf16x8 v = *reinterpret_cast<const bf16x8*>(
                    zx + (size_t)(g + k - 3) * NZX + DINNER + c0 + lc8);
                #pragma unroll
                for (int m = 0; m < 8; ++m)
                    acc[m] += cwS[(lc8 + m) * 4 + k] * (float)v[m];
            }
        }
        bf16x8 o;
        #pragma unroll
        for (int m = 0; m < 8; ++m) o[m] = (bf16_t)siluf(acc[m]);
        *reinterpret_cast<bf16x8*>(xbc + (size_t)g * NCONV + c0 + lc8) = o;
        if (cg < 9) {
            bf16x4 lo, hi;
            #pragma unroll
            for (int m = 0; m < 4; ++m) { lo[m] = o[m]; hi[m] = o[m + 4]; }
            *reinterpret_cast<bf16x4*>(&tile[row * TS + lc8]) = lo;
            *reinterpret_cast<bf16x4*>(&tile[row * TS + lc8 + 4]) = hi;
        }
    }
    if (cg == 9) return;
    __syncthreads();

    const bool isB = (cg == 8);
    int jo = (tid >> 4) * 8;
    float sc[8];
    #pragma unroll
    for (int m = 0; m < 8; ++m)
        sc[m] = isB ? EdTv[bc * 128 + jo + m] : 1.f;

    #pragma unroll
    for (int pass = 0; pass < 8; ++pass) {
        int oc = pass * 16 + (tid & 15);
        bf16x8 o;
        #pragma unroll
        for (int m = 0; m < 8; ++m)
            o[m] = (bf16_t)((float)tile[(jo + m) * TS + oc] * sc[m]);
        bf16_t* dst = isB
            ? (Bwt + (size_t)bc * 16384 + (size_t)oc * 128 + jo)
            : (Xt + (size_t)bc * 131072 + ((size_t)c0 + oc) * 128 + jo);
        *reinterpret_cast<bf16x8*>(dst) = o;
    }
}

// ---------------------------------------------------------------------------
// Sequential chunk combine: S_init(c) = chp(c-1)*S_init(c-1) + S_loc(c-1)
// ---------------------------------------------------------------------------
__global__ __launch_bounds__(256) void scan_combine_kernel(
    const bf16_t* __restrict__ cstate, const float* __restrict__ chp,
    bf16_t* __restrict__ Stb)
{
    int idx = blockIdx.x * 256 + threadIdx.x;   // B * 131072
    int b   = idx >> 17;
    int np  = idx & 131071;
    float v = 0.f;
    for (int c = 0; c < NCHUNK; ++c) {
        size_t off = ((size_t)(b * NCHUNK + c) << 17) + np;
        Stb[off] = (bf16_t)v;
        float tmp = (float)cstate[off];
        v = chp[b * NCHUNK + c] * v + tmp;
    }
}

// ---------------------------------------------------------------------------
// mbuild (fused GEMM-G): per chunk, stage C,B tiles (swizzled), MFMA
// G = C@B^T, then write Mx = [mask-decay(G) | P*C] bf16.
// ---------------------------------------------------------------------------
__global__ __launch_bounds__(256) void mbuild_kernel(
    const float* __restrict__ sarr, const float* __restrict__ dtv,
    const float* __restrict__ Pv, const float* __restrict__ A_log,
    const bf16_t* __restrict__ xbc, bf16_t* __restrict__ Mx)
{
    __shared__ __align__(16) bf16_t Cs[128 * 128];
    __shared__ __align__(16) bf16_t Bs2[128 * 128];
    __shared__ float sj[CHUNK], dj[CHUNK], pj[CHUNK];

    int bc = blockIdx.x, tid = threadIdx.x;
    if (tid < CHUNK) {
        sj[tid] = sarr[bc * CHUNK + tid];
        dj[tid] = dtv[bc * CHUNK + tid];
        pj[tid] = Pv[bc * CHUNK + tid];
    }
    int rowbase = bc * 128;
    int srow = tid >> 4;
    int gsw  = (((tid & 15) ^ (srow & 7))) * 8;
    int lsl  = (tid & 15) * 8;
    #pragma unroll
    for (int i = 0; i < 8; ++i) {
        int row = srow + i * 16;
        load_lds16(&xbc[(size_t)(rowbase + row) * NCONV + 1152 + gsw], &Cs[row * 128 + lsl]);
        load_lds16(&xbc[(size_t)(rowbase + row) * NCONV + 1024 + gsw], &Bs2[row * 128 + lsl]);
    }
    __syncthreads();

    const int wave = tid >> 6, lane = tid & 63;
    const int lr = lane & 15, q = lane >> 4;
    const int wm = (wave & 1) * 64, wn = (wave >> 1) * 64;

    f32x4 acc[4][4];
    #pragma unroll
    for (int i = 0; i < 4; ++i)
        #pragma unroll
        for (int j = 0; j < 4; ++j)
            acc[i][j] = (f32x4){0.f, 0.f, 0.f, 0.f};

    #pragma unroll
    for (int k0 = 0; k0 < 128; k0 += 32) {
        bf16x8 af[4], bfr[4];
        #pragma unroll
        for (int mi = 0; mi < 4; ++mi) {
            int r = wm + mi * 16 + lr, kc = (k0 >> 3) + q;
            af[mi] = *reinterpret_cast<const bf16x8*>(
                &Cs[r * 128 + ((kc ^ (r & 7)) << 3)]);
        }
        #pragma unroll
        for (int ni = 0; ni < 4; ++ni) {
            int r = wn + ni * 16 + lr, kc = (k0 >> 3) + q;
            bfr[ni] = *reinterpret_cast<const bf16x8*>(
                &Bs2[r * 128 + ((kc ^ (r & 7)) << 3)]);
        }
        #pragma unroll
        for (int mi = 0; mi < 4; ++mi)
            #pragma unroll
            for (int ni = 0; ni < 4; ++ni)
                acc[mi][ni] = __builtin_amdgcn_mfma_f32_16x16x32_bf16(
                    af[mi], bfr[ni], acc[mi][ni], 0, 0, 0);
    }

    float A = -expf(A_log[0]);
    bf16_t* MxB = Mx + (size_t)bc * 32768;
    #pragma unroll
    for (int mi = 0; mi < 4; ++mi)
        #pragma unroll
        for (int ni = 0; ni < 4; ++ni)
            #pragma unroll
            for (int ri = 0; ri < 4; ++ri) {
                int row = wm + mi * 16 + q * 4 + ri;
                int col = wn + ni * 16 + lr;
                float val = 0.f;
                if (col <= row)
                    val = acc[mi][ni][ri] * expf(A * (sj[row] - sj[col])) * dj[col];
                MxB[(size_t)row * 256 + col] = (bf16_t)val;
            }

    // Cw half from LDS (undo swizzle): Mx[row][128+n] = P_row * C[row][n]
    int rr = tid >> 1, cb2 = (tid & 1) * 64;
    float Pi = pj[rr];
    #pragma unroll
    for (int m0 = 0; m0 < 64; m0 += 8) {
        int kc = (cb2 + m0) >> 3;
        bf16x8 cv = *reinterpret_cast<const bf16x8*>(
            &Cs[rr * 128 + ((kc ^ (rr & 7)) << 3)]);
        bf16x8 o;
        #pragma unroll
        for (int m = 0; m < 8; ++m) o[m] = (bf16_t)((float)cv[m] * Pi);
        *reinterpret_cast<bf16x8*>(&MxB[(size_t)rr * 256 + 128 + cb2 + m0]) = o;
    }
}

// ---------------------------------------------------------------------------
// Gate + RMSNorm (+ fused rnn passthrough in tail blocks)
// ---------------------------------------------------------------------------
__global__ __launch_bounds__(256) void gate_norm_kernel(
    const bf16_t* __restrict__ yf, const bf16_t* __restrict__ zx,
    const bf16_t* __restrict__ xbc, const float* __restrict__ Dp,
    const float* __restrict__ norm_w, bf16_t* __restrict__ yb,
    const float* __restrict__ rnn, float* __restrict__ outTail)
{
    __shared__ float red[4];
    int r = blockIdx.x, tid = threadIdx.x;
    if (r >= MROWS) {
        int i = (r - MROWS) * 256 + tid;
        if (i < BATCH * DMODEL) outTail[i] = rnn[i];
        return;
    }
    int p = tid * 4;
    float D0 = Dp[0];
    bf16x4 yv = *reinterpret_cast<const bf16x4*>(yf + (size_t)r * DINNER + p);
    bf16x4 zv = *reinterpret_cast<const bf16x4*>(zx + (size_t)r * NZX + p);
    bf16x4 xv = *reinterpret_cast<const bf16x4*>(xbc + (size_t)r * NCONV + p);
    float g0 = ((float)yv[0] + D0 * (float)xv[0]) * siluf((float)zv[0]);
    float g1 = ((float)yv[1] + D0 * (float)xv[1]) * siluf((float)zv[1]);
    float g2 = ((float)yv[2] + D0 * (float)xv[2]) * siluf((float)zv[2]);
    float g3 = ((float)yv[3] + D0 * (float)xv[3]) * siluf((float)zv[3]);
    float ss = g0 * g0 + g1 * g1 + g2 * g2 + g3 * g3;
    #pragma unroll
    for (int m = 32; m >= 1; m >>= 1) ss += __shfl_xor(ss, m);
    if ((tid & 63) == 0) red[tid >> 6] = ss;
    __syncthreads();
    float tot = red[0] + red[1] + red[2] + red[3];
    float scale = rsqrtf(tot * (1.f / 1024.f) + 1e-5f);
    float4 nw = *reinterpret_cast<const float4*>(norm_w + p);
    bf16x4 o;
    o[0] = (bf16_t)(g0 * scale * nw.x);
    o[1] = (bf16_t)(g1 * scale * nw.y);
    o[2] = (bf16_t)(g2 * scale * nw.z);
    o[3] = (bf16_t)(g3 * scale * nw.w);
    *reinterpret_cast<bf16x4*>(yb + (size_t)r * DINNER + p) = o;
}

// ---------------------------------------------------------------------------
extern "C" void kernel_launch(void* const* d_in, const int* in_sizes, int n_in,
                              void* d_out, int out_size, void* d_ws, size_t ws_size,
                              hipStream_t stream)
{
    const float* x        = (const float*)d_in[0];
    const float* rnn      = (const float*)d_in[1];
    const float* W_in     = (const float*)d_in[2];
    const float* conv_w   = (const float*)d_in[3];
    const float* conv_b   = (const float*)d_in[4];
    const float* dt_bias  = (const float*)d_in[5];
    const float* A_log    = (const float*)d_in[6];
    const float* Dp       = (const float*)d_in[7];
    const float* norm_w   = (const float*)d_in[8];
    const float* W_out    = (const float*)d_in[9];
    float* out = (float*)d_out;

    // workspace carve
    char* ws = (char*)d_ws;
    bf16_t* xb     = (bf16_t*)(ws + 0);                       //  8,388,608 (dead after GEMM1)
    bf16_t* Mx     = (bf16_t*)(ws + 4194304);                 //  4,194,304 (alias over xb tail)
    bf16_t* winb   = (bf16_t*)(ws + 8388608);                 //  2,360,320
    bf16_t* woutb  = (bf16_t*)(ws + 10748928);                //  1,048,576
    bf16_t* zx     = (bf16_t*)(ws + 11797504);                // 37,748,736
    float*  dtv    = (float*) (ws + 49546240);                //     32,768
    float*  sarr   = (float*) (ws + 49579008);                //     32,768
    float*  Pv     = (float*) (ws + 49611776);                //     32,768
    float*  EdTv   = (float*) (ws + 49644544);                //     32,768
    float*  chp    = (float*) (ws + 49677312);                //        256
    bf16_t* xbcb   = (bf16_t*)(ws + 49677568);                // 20,971,520
    bf16_t* Xt     = (bf16_t*)(ws + 70649088);                // 16,777,216
    bf16_t* Bwt    = (bf16_t*)(ws + 87426304);                //  2,097,152
    bf16_t* cstate = (bf16_t*)(ws + 89523456);                // 16,777,216 (S_loc bf16)
    bf16_t* yf     = (bf16_t*)(ws + 89523456);                // alias over dead cstate
    bf16_t* Stb    = (bf16_t*)(ws + 106300672);               // 16,777,216
    bf16_t* yb     = (bf16_t*)(ws + 123077888);               // 16,777,216
    // end: 139,855,104 bytes

    // 1) dt (fp32) + x cast + weight casts (one kernel, block-range split)
    {
        const int n4a = 2305 * DMODEL / 4, n4b = DMODEL * DINNER / 4;
        int grid = MROWS / 4 + (n4a + n4b + 255) / 256;
        dtcast_kernel<<<grid, 256, 0, stream>>>(
            x, W_in, dt_bias, W_out, dtv, xb, winb, woutb);
    }

    // 2) GEMM1 (XCD-swizzled, + fused cumsum tail blocks)
    gemm1_kernel<<<1152 + NBC, 256, 0, stream>>>(
        xb, winb, zx, dtv, A_log, sarr, Pv, EdTv, chp);

    // 3) fused conv + transpose (writes xbcb, Xt, Bwt)
    conv_tr_kernel<<<dim3(10, NBC), 256, 0, stream>>>(
        zx, conv_w, conv_b, EdTv, xbcb, Xt, Bwt);

    // 4) GEMM-A: S_loc[p,n] = Xt @ Bwt^T  (per chunk, bf16 out)
    gemm_bt_kernel<bf16_t><<<dim3(1, 8, NBC), 256, 0, stream>>>(
        Xt, Bwt, cstate, DSTATE, CHUNK, CHUNK, CHUNK,
        131072, 16384, 131072);

    // 5) combine -> Stb bf16 (S_init per chunk, [p,n])
    scan_combine_kernel<<<BATCH * 131072 / 256, 256, 0, stream>>>(cstate, chp, Stb);

    // 6) mbuild (fused G-GEMM): Mx = [decay-masked C@B^T | P*C]
    mbuild_kernel<<<NBC, 256, 0, stream>>>(sarr, dtv, Pv, A_log, xbcb, Mx);

    // 7) GEMM-Y: yf[i,p] = Mx @ [Xt;Stb]^T  (bf16 out)
    gemm_y_kernel<<<dim3(8, 1, NBC), 256, 0, stream>>>(Mx, Xt, Stb, yf);

    // 8) gate + RMSNorm -> yb bf16 (+ rnn passthrough tail blocks)
    gate_norm_kernel<<<MROWS + 8, 256, 0, stream>>>(
        yf, zx, xbcb, Dp, norm_w, yb, rnn, out + (size_t)MROWS * DMODEL);

    // 9) GEMM2: out[8192,512] = yb @ woutb^T (f32, into d_out, XCD-swizzled)
    gemm2_kernel<<<256, 256, 0, stream>>>(yb, woutb, out);
}

// Round 11
// 219.036 us; speedup vs baseline: 1.0768x; 1.0692x over previous
//
#include <hip/hip_runtime.h>
#include <cstdint>
#include <cstddef>

// ---------------------------------------------------------------------------
// Mamba2 layer forward (B=4, L=2048, d_model=512, d_inner=1024, d_state=128,
// nheads=1, d_conv=4). SSD formulation: scan as chunked bf16 MFMA GEMMs.
// R5 SSD 609->281; R6 global_load_lds 281->263; R7 XOR-swizzle 263->253;
// R8 fusion/traffic 253->233; R9 epilogue repack regressed (reverted);
// R10 XCD grid swizzle (GEMM1 out of top-5) but conv_tr exposed: 47us,
// 13.1M LDS conflict cycles (TS=132 -> even bank stride -> 4-way on BOTH
// phases). R11: conv_tr rebuilt — 128x64 tile, TS=66 (odd bank stride ->
// 2-way=free both phases, verified per-wave bank arithmetic), bf16x2
// writes, 1280 blocks (2x parallelism), XCD-matched bc mapping.
// ---------------------------------------------------------------------------

typedef __bf16 bf16_t;
typedef __bf16 bf16x8 __attribute__((ext_vector_type(8)));
typedef __bf16 bf16x4 __attribute__((ext_vector_type(4)));
typedef __bf16 bf16x2 __attribute__((ext_vector_type(2)));
typedef float  f32x4  __attribute__((ext_vector_type(4)));

#define BATCH   4
#define SEQLEN  2048
#define MROWS   8192
#define DMODEL  512
#define DINNER  1024
#define DSTATE  128
#define NZX     2304
#define NCONV   1280
#define CHUNK   128
#define NCHUNK  16
#define NBC     64            // BATCH * NCHUNK

__device__ __forceinline__ float siluf(float x) { return x / (1.f + __expf(-x)); }

// async global->LDS, 16B per lane. LDS dst is wave-uniform base + lane*16.
__device__ __forceinline__ void load_lds16(const bf16_t* g, bf16_t* l)
{
    __builtin_amdgcn_global_load_lds(
        (const __attribute__((address_space(1))) void*)g,
        (__attribute__((address_space(3))) void*)l,
        16, 0, 0);
}

// ---------------------------------------------------------------------------
// GEMM body: C[m,n] = sum_k A[m*lda+k] * B[n*ldb+k]; 128x128 tile, BK=64,
// XOR-swizzled global_load_lds staging; direct-store epilogue.
// ---------------------------------------------------------------------------
template <typename OutT>
__device__ __forceinline__ void gemm_body(
    const bf16_t* __restrict__ A, const bf16_t* __restrict__ B,
    OutT* __restrict__ C, int Ntot, int K, int lda, int ldb, int bn, int bm)
{
    __shared__ __align__(16) bf16_t As[128 * 64];
    __shared__ __align__(16) bf16_t Bs[128 * 64];

    const int tid  = threadIdx.x;
    const int wave = tid >> 6, lane = tid & 63;
    const int lr = lane & 15, q = lane >> 4;
    const int wm = (wave & 1) * 64, wn = (wave >> 1) * 64;

    f32x4 acc[4][4];
    #pragma unroll
    for (int i = 0; i < 4; ++i)
        #pragma unroll
        for (int j = 0; j < 4; ++j)
            acc[i][j] = (f32x4){0.f, 0.f, 0.f, 0.f};

    const int row_a0 = bm * 128, row_b0 = bn * 128;
    const int srow = tid >> 3;
    const int gsw  = (((tid & 7) ^ (srow & 7))) * 8;   // swizzled global chunk
    const int lsl  = (tid & 7) * 8;                    // natural LDS slot

    for (int kt = 0; kt < K; kt += 64) {
        #pragma unroll
        for (int i = 0; i < 4; ++i) {
            int row = srow + i * 32;
            load_lds16(&A[(size_t)(row_a0 + row) * lda + kt + gsw], &As[row * 64 + lsl]);
            load_lds16(&B[(size_t)(row_b0 + row) * ldb + kt + gsw], &Bs[row * 64 + lsl]);
        }
        __syncthreads();
        #pragma unroll
        for (int k0 = 0; k0 < 64; k0 += 32) {
            bf16x8 af[4], bfr[4];
            #pragma unroll
            for (int mi = 0; mi < 4; ++mi) {
                int r = wm + mi * 16 + lr, kc = (k0 >> 3) + q;
                af[mi] = *reinterpret_cast<const bf16x8*>(
                    &As[r * 64 + ((kc ^ (r & 7)) << 3)]);
            }
            #pragma unroll
            for (int ni = 0; ni < 4; ++ni) {
                int r = wn + ni * 16 + lr, kc = (k0 >> 3) + q;
                bfr[ni] = *reinterpret_cast<const bf16x8*>(
                    &Bs[r * 64 + ((kc ^ (r & 7)) << 3)]);
            }
            #pragma unroll
            for (int mi = 0; mi < 4; ++mi)
                #pragma unroll
                for (int ni = 0; ni < 4; ++ni)
                    acc[mi][ni] = __builtin_amdgcn_mfma_f32_16x16x32_bf16(
                        af[mi], bfr[ni], acc[mi][ni], 0, 0, 0);
        }
        __syncthreads();
    }

    #pragma unroll
    for (int mi = 0; mi < 4; ++mi)
        #pragma unroll
        for (int ni = 0; ni < 4; ++ni)
            #pragma unroll
            for (int ri = 0; ri < 4; ++ri) {
                int row = row_a0 + wm + mi * 16 + q * 4 + ri;
                int col = row_b0 + wn + ni * 16 + lr;
                C[(size_t)row * Ntot + col] = (OutT)acc[mi][ni][ri];
            }
}

// batched wrapper (GEMM-A)
template <typename OutT>
__global__ __launch_bounds__(256) void gemm_bt_kernel(
    const bf16_t* __restrict__ A, const bf16_t* __restrict__ B,
    OutT* __restrict__ C, int Ntot, int K, int lda, int ldb,
    size_t sA, size_t sB, size_t sC)
{
    gemm_body<OutT>(A + (size_t)blockIdx.z * sA, B + (size_t)blockIdx.z * sB,
                    C + (size_t)blockIdx.z * sC, Ntot, K, lda, ldb,
                    blockIdx.x, blockIdx.y);
}

// ---------------------------------------------------------------------------
// cumsum body (per chunk bc, active threads 0..127): decay scalars.
// ---------------------------------------------------------------------------
__device__ __forceinline__ void cumsum_body(
    const float* __restrict__ dtv, const float* __restrict__ A_log,
    float* __restrict__ sarr, float* __restrict__ Pv,
    float* __restrict__ EdTv, float* __restrict__ chp, int bc)
{
    __shared__ float w0sum, stot;
    int j = threadIdx.x;
    bool active = j < CHUNK;
    int lane = j & 63;
    int r = bc * CHUNK + j;
    float A = -expf(A_log[0]);
    float dt = active ? dtv[r] : 0.f;
    float s = dt;
    #pragma unroll
    for (int m = 1; m <= 32; m <<= 1) {
        float o = __shfl_up(s, m);
        if (lane >= m) s += o;
    }
    if (j == 63) w0sum = s;
    __syncthreads();
    if (j >= 64 && active) s += w0sum;
    if (j == 127) stot = s;
    __syncthreads();
    if (active) {
        float sT = stot;
        sarr[r] = s;
        Pv[r]   = expf(A * s);
        EdTv[r] = expf(A * (sT - s)) * dt;
        if (j == 127) chp[bc] = expf(A * sT);
    }
}

// GEMM1 (XCD-aware swizzle: per-XCD bm band) + fused cumsum (tail blocks)
__global__ __launch_bounds__(256) void gemm1_kernel(
    const bf16_t* __restrict__ xb, const bf16_t* __restrict__ winb,
    bf16_t* __restrict__ zx, const float* __restrict__ dtv,
    const float* __restrict__ A_log, float* __restrict__ sarr,
    float* __restrict__ Pv, float* __restrict__ EdTv, float* __restrict__ chp)
{
    int linear = blockIdx.x;
    if (linear < (NZX / 128) * (MROWS / 128)) {     // 18*64 = 1152
        int xcd = linear & 7, j = linear >> 3;      // j in [0,144)
        int bm = xcd * 8 + (j & 7);                 // 8-row bm band per XCD
        int bn = j >> 3;                            // [0,18)
        gemm_body<bf16_t>(xb, winb, zx, NZX, DMODEL, DMODEL, DMODEL, bn, bm);
    } else {
        cumsum_body(dtv, A_log, sarr, Pv, EdTv, chp, linear - 1152);
    }
}

// GEMM2 with the same XCD-aware swizzle (256 blocks: 4 bn x 64 bm)
__global__ __launch_bounds__(256) void gemm2_kernel(
    const bf16_t* __restrict__ yb, const bf16_t* __restrict__ woutb,
    float* __restrict__ out)
{
    int linear = blockIdx.x;                        // [0,256)
    int xcd = linear & 7, j = linear >> 3;          // j in [0,32)
    int bm = xcd * 8 + (j & 7);
    int bn = j >> 3;                                // [0,4)
    gemm_body<float>(yb, woutb, out, DMODEL, DINNER, DINNER, DINNER, bn, bm);
}

// ---------------------------------------------------------------------------
// Y-GEMM: Y[i,p] = sum_{k<256} Mx[i,k] * Dx[p,k]; Dx = [Xt | Stb] per chunk.
// ---------------------------------------------------------------------------
__global__ __launch_bounds__(256) void gemm_y_kernel(
    const bf16_t* __restrict__ Mx, const bf16_t* __restrict__ Xt,
    const bf16_t* __restrict__ Stb, bf16_t* __restrict__ yf)
{
    __shared__ __align__(16) bf16_t As[128 * 64];
    __shared__ __align__(16) bf16_t Bs[128 * 64];

    const int bc = blockIdx.z, bn = blockIdx.x;
    const bf16_t* Ab = Mx + (size_t)bc * 32768;                      // 128x256
    const bf16_t* Xb = Xt  + (size_t)bc * 131072 + (size_t)bn * 128 * 128;
    const bf16_t* Sb = Stb + (size_t)bc * 131072 + (size_t)bn * 128 * 128;
    bf16_t* Cb = yf + (size_t)bc * 131072;

    const int tid  = threadIdx.x;
    const int wave = tid >> 6, lane = tid & 63;
    const int lr = lane & 15, q = lane >> 4;
    const int wm = (wave & 1) * 64, wn = (wave >> 1) * 64;

    f32x4 acc[4][4];
    #pragma unroll
    for (int i = 0; i < 4; ++i)
        #pragma unroll
        for (int j = 0; j < 4; ++j)
            acc[i][j] = (f32x4){0.f, 0.f, 0.f, 0.f};

    const int srow = tid >> 3;
    const int gsw  = (((tid & 7) ^ (srow & 7))) * 8;
    const int lsl  = (tid & 7) * 8;

    for (int kt = 0; kt < 256; kt += 64) {
        const bf16_t* bsrc = (kt < 128) ? (Xb + kt) : (Sb + (kt - 128));
        #pragma unroll
        for (int i = 0; i < 4; ++i) {
            int row = srow + i * 32;
            load_lds16(&Ab[(size_t)row * 256 + kt + gsw], &As[row * 64 + lsl]);
            load_lds16(&bsrc[(size_t)row * 128 + gsw], &Bs[row * 64 + lsl]);
        }
        __syncthreads();
        #pragma unroll
        for (int k0 = 0; k0 < 64; k0 += 32) {
            bf16x8 af[4], bfr[4];
            #pragma unroll
            for (int mi = 0; mi < 4; ++mi) {
                int r = wm + mi * 16 + lr, kc = (k0 >> 3) + q;
                af[mi] = *reinterpret_cast<const bf16x8*>(
                    &As[r * 64 + ((kc ^ (r & 7)) << 3)]);
            }
            #pragma unroll
            for (int ni = 0; ni < 4; ++ni) {
                int r = wn + ni * 16 + lr, kc = (k0 >> 3) + q;
                bfr[ni] = *reinterpret_cast<const bf16x8*>(
                    &Bs[r * 64 + ((kc ^ (r & 7)) << 3)]);
            }
            #pragma unroll
            for (int mi = 0; mi < 4; ++mi)
                #pragma unroll
                for (int ni = 0; ni < 4; ++ni)
                    acc[mi][ni] = __builtin_amdgcn_mfma_f32_16x16x32_bf16(
                        af[mi], bfr[ni], acc[mi][ni], 0, 0, 0);
        }
        __syncthreads();
    }

    #pragma unroll
    for (int mi = 0; mi < 4; ++mi)
        #pragma unroll
        for (int ni = 0; ni < 4; ++ni)
            #pragma unroll
            for (int ri = 0; ri < 4; ++ri) {
                int row = wm + mi * 16 + q * 4 + ri;
                int col = bn * 128 + wn + ni * 16 + lr;
                Cb[(size_t)row * 1024 + col] = (bf16_t)acc[mi][ni][ri];
            }
}

// ---------------------------------------------------------------------------
// Fused: dt column (one wave per row, fp32 exact) + x->bf16 cast  [blocks
// 0..2047], then W_in/W_out -> bf16 casts [blocks 2048..].
// ---------------------------------------------------------------------------
__global__ __launch_bounds__(256) void dtcast_kernel(
    const float* __restrict__ x, const float* __restrict__ W_in,
    const float* __restrict__ dt_bias, const float* __restrict__ W_out,
    float* __restrict__ dtv, bf16_t* __restrict__ xb,
    bf16_t* __restrict__ winb, bf16_t* __restrict__ woutb)
{
    int bid = blockIdx.x;
    if (bid < MROWS / 4) {
        int wave = threadIdx.x >> 6, lane = threadIdx.x & 63;
        int r = bid * 4 + wave;
        const float* xr = x + (size_t)r * DMODEL + lane * 8;
        const float* wr = W_in + (size_t)NZX * DMODEL + lane * 8;
        float4 a0 = *reinterpret_cast<const float4*>(xr);
        float4 a1 = *reinterpret_cast<const float4*>(xr + 4);
        float4 b0 = *reinterpret_cast<const float4*>(wr);
        float4 b1 = *reinterpret_cast<const float4*>(wr + 4);

        bf16x8 xo;
        xo[0] = (bf16_t)a0.x; xo[1] = (bf16_t)a0.y; xo[2] = (bf16_t)a0.z; xo[3] = (bf16_t)a0.w;
        xo[4] = (bf16_t)a1.x; xo[5] = (bf16_t)a1.y; xo[6] = (bf16_t)a1.z; xo[7] = (bf16_t)a1.w;
        *reinterpret_cast<bf16x8*>(xb + (size_t)r * DMODEL + lane * 8) = xo;

        float s = a0.x * b0.x + a0.y * b0.y + a0.z * b0.z + a0.w * b0.w
                + a1.x * b1.x + a1.y * b1.y + a1.z * b1.z + a1.w * b1.w;
        #pragma unroll
        for (int m = 32; m >= 1; m >>= 1) s += __shfl_xor(s, m);
        if (lane == 0) {
            float t  = s + dt_bias[0];
            dtv[r] = (t > 20.f) ? t : log1pf(expf(t));
        }
        return;
    }
    int i = (bid - MROWS / 4) * 256 + threadIdx.x;
    const int n4a = 2305 * DMODEL / 4, n4b = DMODEL * DINNER / 4;
    const float* src; bf16_t* dst; int j;
    if (i < n4a)            { src = W_in;  dst = winb;  j = i; }
    else if (i < n4a + n4b) { src = W_out; dst = woutb; j = i - n4a; }
    else return;
    float4 v = reinterpret_cast<const float4*>(src)[j];
    bf16x4 o;
    o[0] = (bf16_t)v.x; o[1] = (bf16_t)v.y; o[2] = (bf16_t)v.z; o[3] = (bf16_t)v.w;
    reinterpret_cast<bf16x4*>(dst)[j] = o;
}

// ---------------------------------------------------------------------------
// Fused conv + transpose, R11 layout: 1280 blocks, each (cg 0..9, half 0..1,
// chunk bc) covers 128 rows x 64 channels.  Tile [j=128][ch=64], TS=66
// (odd bank stride -> both phases 2-way = free).  bc mapped so the block
// runs on the XCD whose L2 holds zx band bc (GEMM1 swizzle: band bm on
// XCD bm>>3).
//   cg<8:  Xt[bc][c0+oc][j] (decay 1)      cg==8: Bwt (EdTv-scaled)
//   cg==9: conv only (C columns)
// ---------------------------------------------------------------------------
__global__ __launch_bounds__(256) void conv_tr_kernel(
    const bf16_t* __restrict__ zx, const float* __restrict__ cw,
    const float* __restrict__ cb, const float* __restrict__ EdTv,
    bf16_t* __restrict__ xbc, bf16_t* __restrict__ Xt, bf16_t* __restrict__ Bwt)
{
    constexpr int TS = 66;                 // 132B row stride = 33 banks (odd)
    __shared__ bf16_t tile[128 * TS];      // [j][ch_local]
    __shared__ float cwS[64 * 4];
    __shared__ float cbS[64];

    int id  = blockIdx.x;                  // [0,1280)
    int xcd = id & 7;
    int k   = id >> 3;                     // [0,160)
    int bc  = xcd * 8 + (k & 7);           // zx band bc lives in XCD bc>>3 L2
    int rest = k >> 3;                     // [0,20)
    int cg   = rest >> 1;                  // [0,10)
    int half = rest & 1;
    int c0   = cg * 128 + half * 64;       // global channel base in [0,1280)
    int tid  = threadIdx.x;

    if (tid < 64) {
        float4 w = *reinterpret_cast<const float4*>(cw + (size_t)(c0 + tid) * 4);
        *reinterpret_cast<float4*>(&cwS[tid * 4]) = w;
        cbS[tid] = cb[c0 + tid];
    }
    __syncthreads();

    int lrow = tid >> 3;                   // 0..31
    int lc8  = (tid & 7) * 8;              // 0..56 (channel-local)
    int g0 = bc * 128;

    #pragma unroll
    for (int pass = 0; pass < 4; ++pass) {
        int row = pass * 32 + lrow;        // j in chunk
        int g = g0 + row;
        int l = g & (SEQLEN - 1);
        float acc[8];
        #pragma unroll
        for (int m = 0; m < 8; ++m) acc[m] = cbS[lc8 + m];
        #pragma unroll
        for (int kk = 0; kk < 4; ++kk) {
            if (l + kk >= 3) {
                bf16x8 v = *reinterpret_cast<const bf16x8*>(
                    zx + (size_t)(g + kk - 3) * NZX + DINNER + c0 + lc8);
                #pragma unroll
                for (int m = 0; m < 8; ++m)
                    acc[m] += cwS[(lc8 + m) * 4 + kk] * (float)v[m];
            }
        }
        bf16x8 o;
        #pragma unroll
        for (int m = 0; m < 8; ++m) o[m] = (bf16_t)siluf(acc[m]);
        *reinterpret_cast<bf16x8*>(xbc + (size_t)g * NCONV + c0 + lc8) = o;
        if (cg < 9) {
            #pragma unroll
            for (int jj = 0; jj < 4; ++jj) {
                bf16x2 p; p[0] = o[jj * 2]; p[1] = o[jj * 2 + 1];
                *reinterpret_cast<bf16x2*>(&tile[row * TS + lc8 + jj * 2]) = p;
            }
        }
    }
    if (cg == 9) return;
    __syncthreads();

    const bool isB = (cg == 8);
    int jo = (tid >> 4) * 8;               // j-block 0..120
    int i  = tid & 15;
    float sc[8];
    #pragma unroll
    for (int m = 0; m < 8; ++m)
        sc[m] = isB ? EdTv[bc * 128 + jo + m] : 1.f;

    #pragma unroll
    for (int pass = 0; pass < 4; ++pass) {
        int oc = pass * 16 + i;            // channel-local 0..63
        bf16x8 o;
        #pragma unroll
        for (int m = 0; m < 8; ++m)
            o[m] = (bf16_t)((float)tile[(jo + m) * TS + oc] * sc[m]);
        bf16_t* dst = isB
            ? (Bwt + (size_t)bc * 16384 + (size_t)(c0 - 1024 + oc) * 128 + jo)
            : (Xt + (size_t)bc * 131072 + (size_t)(c0 + oc) * 128 + jo);
        *reinterpret_cast<bf16x8*>(dst) = o;
    }
}

// ---------------------------------------------------------------------------
// Sequential chunk combine: S_init(c) = chp(c-1)*S_init(c-1) + S_loc(c-1)
// ---------------------------------------------------------------------------
__global__ __launch_bounds__(256) void scan_combine_kernel(
    const bf16_t* __restrict__ cstate, const float* __restrict__ chp,
    bf16_t* __restrict__ Stb)
{
    int idx = blockIdx.x * 256 + threadIdx.x;   // B * 131072
    int b   = idx >> 17;
    int np  = idx & 131071;
    float v = 0.f;
    for (int c = 0; c < NCHUNK; ++c) {
        size_t off = ((size_t)(b * NCHUNK + c) << 17) + np;
        Stb[off] = (bf16_t)v;
        float tmp = (float)cstate[off];
        v = chp[b * NCHUNK + c] * v + tmp;
    }
}

// ---------------------------------------------------------------------------
// mbuild (fused GEMM-G): per chunk, stage C,B tiles (swizzled), MFMA
// G = C@B^T, then write Mx = [mask-decay(G) | P*C] bf16.
// ---------------------------------------------------------------------------
__global__ __launch_bounds__(256) void mbuild_kernel(
    const float* __restrict__ sarr, const float* __restrict__ dtv,
    const float* __restrict__ Pv, const float* __restrict__ A_log,
    const bf16_t* __restrict__ xbc, bf16_t* __restrict__ Mx)
{
    __shared__ __align__(16) bf16_t Cs[128 * 128];
    __shared__ __align__(16) bf16_t Bs2[128 * 128];
    __shared__ float sj[CHUNK], dj[CHUNK], pj[CHUNK];

    int bc = blockIdx.x, tid = threadIdx.x;
    if (tid < CHUNK) {
        sj[tid] = sarr[bc * CHUNK + tid];
        dj[tid] = dtv[bc * CHUNK + tid];
        pj[tid] = Pv[bc * CHUNK + tid];
    }
    int rowbase = bc * 128;
    int srow = tid >> 4;
    int gsw  = (((tid & 15) ^ (srow & 7))) * 8;
    int lsl  = (tid & 15) * 8;
    #pragma unroll
    for (int i = 0; i < 8; ++i) {
        int row = srow + i * 16;
        load_lds16(&xbc[(size_t)(rowbase + row) * NCONV + 1152 + gsw], &Cs[row * 128 + lsl]);
        load_lds16(&xbc[(size_t)(rowbase + row) * NCONV + 1024 + gsw], &Bs2[row * 128 + lsl]);
    }
    __syncthreads();

    const int wave = tid >> 6, lane = tid & 63;
    const int lr = lane & 15, q = lane >> 4;
    const int wm = (wave & 1) * 64, wn = (wave >> 1) * 64;

    f32x4 acc[4][4];
    #pragma unroll
    for (int i = 0; i < 4; ++i)
        #pragma unroll
        for (int j = 0; j < 4; ++j)
            acc[i][j] = (f32x4){0.f, 0.f, 0.f, 0.f};

    #pragma unroll
    for (int k0 = 0; k0 < 128; k0 += 32) {
        bf16x8 af[4], bfr[4];
        #pragma unroll
        for (int mi = 0; mi < 4; ++mi) {
            int r = wm + mi * 16 + lr, kc = (k0 >> 3) + q;
            af[mi] = *reinterpret_cast<const bf16x8*>(
                &Cs[r * 128 + ((kc ^ (r & 7)) << 3)]);
        }
        #pragma unroll
        for (int ni = 0; ni < 4; ++ni) {
            int r = wn + ni * 16 + lr, kc = (k0 >> 3) + q;
            bfr[ni] = *reinterpret_cast<const bf16x8*>(
                &Bs2[r * 128 + ((kc ^ (r & 7)) << 3)]);
        }
        #pragma unroll
        for (int mi = 0; mi < 4; ++mi)
            #pragma unroll
            for (int ni = 0; ni < 4; ++ni)
                acc[mi][ni] = __builtin_amdgcn_mfma_f32_16x16x32_bf16(
                    af[mi], bfr[ni], acc[mi][ni], 0, 0, 0);
    }

    float A = -expf(A_log[0]);
    bf16_t* MxB = Mx + (size_t)bc * 32768;
    #pragma unroll
    for (int mi = 0; mi < 4; ++mi)
        #pragma unroll
        for (int ni = 0; ni < 4; ++ni)
            #pragma unroll
            for (int ri = 0; ri < 4; ++ri) {
                int row = wm + mi * 16 + q * 4 + ri;
                int col = wn + ni * 16 + lr;
                float val = 0.f;
                if (col <= row)
                    val = acc[mi][ni][ri] * expf(A * (sj[row] - sj[col])) * dj[col];
                MxB[(size_t)row * 256 + col] = (bf16_t)val;
            }

    // Cw half from LDS (undo swizzle): Mx[row][128+n] = P_row * C[row][n]
    int rr = tid >> 1, cb2 = (tid & 1) * 64;
    float Pi = pj[rr];
    #pragma unroll
    for (int m0 = 0; m0 < 64; m0 += 8) {
        int kc = (cb2 + m0) >> 3;
        bf16x8 cv = *reinterpret_cast<const bf16x8*>(
            &Cs[rr * 128 + ((kc ^ (rr & 7)) << 3)]);
        bf16x8 o;
        #pragma unroll
        for (int m = 0; m < 8; ++m) o[m] = (bf16_t)((float)cv[m] * Pi);
        *reinterpret_cast<bf16x8*>(&MxB[(size_t)rr * 256 + 128 + cb2 + m0]) = o;
    }
}

// ---------------------------------------------------------------------------
// Gate + RMSNorm (+ fused rnn passthrough in tail blocks)
// ---------------------------------------------------------------------------
__global__ __launch_bounds__(256) void gate_norm_kernel(
    const bf16_t* __restrict__ yf, const bf16_t* __restrict__ zx,
    const bf16_t* __restrict__ xbc, const float* __restrict__ Dp,
    const float* __restrict__ norm_w, bf16_t* __restrict__ yb,
    const float* __restrict__ rnn, float* __restrict__ outTail)
{
    __shared__ float red[4];
    int r = blockIdx.x, tid = threadIdx.x;
    if (r >= MROWS) {
        int i = (r - MROWS) * 256 + tid;
        if (i < BATCH * DMODEL) outTail[i] = rnn[i];
        return;
    }
    int p = tid * 4;
    float D0 = Dp[0];
    bf16x4 yv = *reinterpret_cast<const bf16x4*>(yf + (size_t)r * DINNER + p);
    bf16x4 zv = *reinterpret_cast<const bf16x4*>(zx + (size_t)r * NZX + p);
    bf16x4 xv = *reinterpret_cast<const bf16x4*>(xbc + (size_t)r * NCONV + p);
    float g0 = ((float)yv[0] + D0 * (float)xv[0]) * siluf((float)zv[0]);
    float g1 = ((float)yv[1] + D0 * (float)xv[1]) * siluf((float)zv[1]);
    float g2 = ((float)yv[2] + D0 * (float)xv[2]) * siluf((float)zv[2]);
    float g3 = ((float)yv[3] + D0 * (float)xv[3]) * siluf((float)zv[3]);
    float ss = g0 * g0 + g1 * g1 + g2 * g2 + g3 * g3;
    #pragma unroll
    for (int m = 32; m >= 1; m >>= 1) ss += __shfl_xor(ss, m);
    if ((tid & 63) == 0) red[tid >> 6] = ss;
    __syncthreads();
    float tot = red[0] + red[1] + red[2] + red[3];
    float scale = rsqrtf(tot * (1.f / 1024.f) + 1e-5f);
    float4 nw = *reinterpret_cast<const float4*>(norm_w + p);
    bf16x4 o;
    o[0] = (bf16_t)(g0 * scale * nw.x);
    o[1] = (bf16_t)(g1 * scale * nw.y);
    o[2] = (bf16_t)(g2 * scale * nw.z);
    o[3] = (bf16_t)(g3 * scale * nw.w);
    *reinterpret_cast<bf16x4*>(yb + (size_t)r * DINNER + p) = o;
}

// ---------------------------------------------------------------------------
extern "C" void kernel_launch(void* const* d_in, const int* in_sizes, int n_in,
                              void* d_out, int out_size, void* d_ws, size_t ws_size,
                              hipStream_t stream)
{
    const float* x        = (const float*)d_in[0];
    const float* rnn      = (const float*)d_in[1];
    const float* W_in     = (const float*)d_in[2];
    const float* conv_w   = (const float*)d_in[3];
    const float* conv_b   = (const float*)d_in[4];
    const float* dt_bias  = (const float*)d_in[5];
    const float* A_log    = (const float*)d_in[6];
    const float* Dp       = (const float*)d_in[7];
    const float* norm_w   = (const float*)d_in[8];
    const float* W_out    = (const float*)d_in[9];
    float* out = (float*)d_out;

    // workspace carve
    char* ws = (char*)d_ws;
    bf16_t* xb     = (bf16_t*)(ws + 0);                       //  8,388,608 (dead after GEMM1)
    bf16_t* Mx     = (bf16_t*)(ws + 4194304);                 //  4,194,304 (alias over xb tail)
    bf16_t* winb   = (bf16_t*)(ws + 8388608);                 //  2,360,320
    bf16_t* woutb  = (bf16_t*)(ws + 10748928);                //  1,048,576
    bf16_t* zx     = (bf16_t*)(ws + 11797504);                // 37,748,736
    float*  dtv    = (float*) (ws + 49546240);                //     32,768
    float*  sarr   = (float*) (ws + 49579008);                //     32,768
    float*  Pv     = (float*) (ws + 49611776);                //     32,768
    float*  EdTv   = (float*) (ws + 49644544);                //     32,768
    float*  chp    = (float*) (ws + 49677312);                //        256
    bf16_t* xbcb   = (bf16_t*)(ws + 49677568);                // 20,971,520
    bf16_t* Xt     = (bf16_t*)(ws + 70649088);                // 16,777,216
    bf16_t* Bwt    = (bf16_t*)(ws + 87426304);                //  2,097,152
    bf16_t* cstate = (bf16_t*)(ws + 89523456);                // 16,777,216 (S_loc bf16)
    bf16_t* yf     = (bf16_t*)(ws + 89523456);                // alias over dead cstate
    bf16_t* Stb    = (bf16_t*)(ws + 106300672);               // 16,777,216
    bf16_t* yb     = (bf16_t*)(ws + 123077888);               // 16,777,216
    // end: 139,855,104 bytes

    // 1) dt (fp32) + x cast + weight casts (one kernel, block-range split)
    {
        const int n4a = 2305 * DMODEL / 4, n4b = DMODEL * DINNER / 4;
        int grid = MROWS / 4 + (n4a + n4b + 255) / 256;
        dtcast_kernel<<<grid, 256, 0, stream>>>(
            x, W_in, dt_bias, W_out, dtv, xb, winb, woutb);
    }

    // 2) GEMM1 (XCD-swizzled, + fused cumsum tail blocks)
    gemm1_kernel<<<1152 + NBC, 256, 0, stream>>>(
        xb, winb, zx, dtv, A_log, sarr, Pv, EdTv, chp);

    // 3) fused conv + transpose (1280 blocks, XCD-matched to zx bands)
    conv_tr_kernel<<<1280, 256, 0, stream>>>(
        zx, conv_w, conv_b, EdTv, xbcb, Xt, Bwt);

    // 4) GEMM-A: S_loc[p,n] = Xt @ Bwt^T  (per chunk, bf16 out)
    gemm_bt_kernel<bf16_t><<<dim3(1, 8, NBC), 256, 0, stream>>>(
        Xt, Bwt, cstate, DSTATE, CHUNK, CHUNK, CHUNK,
        131072, 16384, 131072);

    // 5) combine -> Stb bf16 (S_init per chunk, [p,n])
    scan_combine_kernel<<<BATCH * 131072 / 256, 256, 0, stream>>>(cstate, chp, Stb);

    // 6) mbuild (fused G-GEMM): Mx = [decay-masked C@B^T | P*C]
    mbuild_kernel<<<NBC, 256, 0, stream>>>(sarr, dtv, Pv, A_log, xbcb, Mx);

    // 7) GEMM-Y: yf[i,p] = Mx @ [Xt;Stb]^T  (bf16 out)
    gemm_y_kernel<<<dim3(8, 1, NBC), 256, 0, stream>>>(Mx, Xt, Stb, yf);

    // 8) gate + RMSNorm -> yb bf16 (+ rnn passthrough tail blocks)
    gate_norm_kernel<<<MROWS + 8, 256, 0, stream>>>(
        yf, zx, xbcb, Dp, norm_w, yb, rnn, out + (size_t)MROWS * DMODEL);

    // 9) GEMM2: out[8192,512] = yb @ woutb^T (f32, into d_out, XCD-swizzled)
    gemm2_kernel<<<256, 256, 0, stream>>>(yb, woutb, out);
}

// Round 12
// 213.956 us; speedup vs baseline: 1.1024x; 1.0237x over previous
//
#include <hip/hip_runtime.h>
#include <cstdint>
#include <cstddef>

// ---------------------------------------------------------------------------
// Mamba2 layer forward (B=4, L=2048, d_model=512, d_inner=1024, d_state=128,
// nheads=1, d_conv=4). SSD formulation: scan as chunked bf16 MFMA GEMMs.
// R5 SSD 609->281; R6 global_load_lds 281->263; R7 XOR-swizzle 263->253;
// R8 fusion 253->233; R9 epilogue repack regressed (reverted); R10 XCD
// swizzle; R11 conv_tr odd-bank tile 234->219. R12: wave-per-row gate_norm
// (no LDS/barrier, coalesced halves), prefetch-all scan_combine, GEMM-A +
// mbuild merged (one launch). 8 launches.
// ---------------------------------------------------------------------------

typedef __bf16 bf16_t;
typedef __bf16 bf16x8 __attribute__((ext_vector_type(8)));
typedef __bf16 bf16x4 __attribute__((ext_vector_type(4)));
typedef __bf16 bf16x2 __attribute__((ext_vector_type(2)));
typedef float  f32x4  __attribute__((ext_vector_type(4)));

#define BATCH   4
#define SEQLEN  2048
#define MROWS   8192
#define DMODEL  512
#define DINNER  1024
#define DSTATE  128
#define NZX     2304
#define NCONV   1280
#define CHUNK   128
#define NCHUNK  16
#define NBC     64            // BATCH * NCHUNK

__device__ __forceinline__ float siluf(float x) { return x / (1.f + __expf(-x)); }

// async global->LDS, 16B per lane. LDS dst is wave-uniform base + lane*16.
__device__ __forceinline__ void load_lds16(const bf16_t* g, bf16_t* l)
{
    __builtin_amdgcn_global_load_lds(
        (const __attribute__((address_space(1))) void*)g,
        (__attribute__((address_space(3))) void*)l,
        16, 0, 0);
}

// ---------------------------------------------------------------------------
// GEMM body (smem: 32 KB): C[m,n] = sum_k A[m*lda+k]*B[n*ldb+k]; 128x128
// tile, BK=64, XOR-swizzled global_load_lds staging, direct-store epilogue.
// ---------------------------------------------------------------------------
template <typename OutT>
__device__ __forceinline__ void gemm_body(
    unsigned char* smem,
    const bf16_t* __restrict__ A, const bf16_t* __restrict__ B,
    OutT* __restrict__ C, int Ntot, int K, int lda, int ldb, int bn, int bm)
{
    bf16_t* As = (bf16_t*)smem;
    bf16_t* Bs = (bf16_t*)(smem + 16384);

    const int tid  = threadIdx.x;
    const int wave = tid >> 6, lane = tid & 63;
    const int lr = lane & 15, q = lane >> 4;
    const int wm = (wave & 1) * 64, wn = (wave >> 1) * 64;

    f32x4 acc[4][4];
    #pragma unroll
    for (int i = 0; i < 4; ++i)
        #pragma unroll
        for (int j = 0; j < 4; ++j)
            acc[i][j] = (f32x4){0.f, 0.f, 0.f, 0.f};

    const int row_a0 = bm * 128, row_b0 = bn * 128;
    const int srow = tid >> 3;
    const int gsw  = (((tid & 7) ^ (srow & 7))) * 8;   // swizzled global chunk
    const int lsl  = (tid & 7) * 8;                    // natural LDS slot

    for (int kt = 0; kt < K; kt += 64) {
        #pragma unroll
        for (int i = 0; i < 4; ++i) {
            int row = srow + i * 32;
            load_lds16(&A[(size_t)(row_a0 + row) * lda + kt + gsw], &As[row * 64 + lsl]);
            load_lds16(&B[(size_t)(row_b0 + row) * ldb + kt + gsw], &Bs[row * 64 + lsl]);
        }
        __syncthreads();
        #pragma unroll
        for (int k0 = 0; k0 < 64; k0 += 32) {
            bf16x8 af[4], bfr[4];
            #pragma unroll
            for (int mi = 0; mi < 4; ++mi) {
                int r = wm + mi * 16 + lr, kc = (k0 >> 3) + q;
                af[mi] = *reinterpret_cast<const bf16x8*>(
                    &As[r * 64 + ((kc ^ (r & 7)) << 3)]);
            }
            #pragma unroll
            for (int ni = 0; ni < 4; ++ni) {
                int r = wn + ni * 16 + lr, kc = (k0 >> 3) + q;
                bfr[ni] = *reinterpret_cast<const bf16x8*>(
                    &Bs[r * 64 + ((kc ^ (r & 7)) << 3)]);
            }
            #pragma unroll
            for (int mi = 0; mi < 4; ++mi)
                #pragma unroll
                for (int ni = 0; ni < 4; ++ni)
                    acc[mi][ni] = __builtin_amdgcn_mfma_f32_16x16x32_bf16(
                        af[mi], bfr[ni], acc[mi][ni], 0, 0, 0);
        }
        __syncthreads();
    }

    #pragma unroll
    for (int mi = 0; mi < 4; ++mi)
        #pragma unroll
        for (int ni = 0; ni < 4; ++ni)
            #pragma unroll
            for (int ri = 0; ri < 4; ++ri) {
                int row = row_a0 + wm + mi * 16 + q * 4 + ri;
                int col = row_b0 + wn + ni * 16 + lr;
                C[(size_t)row * Ntot + col] = (OutT)acc[mi][ni][ri];
            }
}

// ---------------------------------------------------------------------------
// cumsum body (per chunk bc, active threads 0..127): decay scalars.
// ---------------------------------------------------------------------------
__device__ __forceinline__ void cumsum_body(
    const float* __restrict__ dtv, const float* __restrict__ A_log,
    float* __restrict__ sarr, float* __restrict__ Pv,
    float* __restrict__ EdTv, float* __restrict__ chp, int bc)
{
    __shared__ float w0sum, stot;
    int j = threadIdx.x;
    bool active = j < CHUNK;
    int lane = j & 63;
    int r = bc * CHUNK + j;
    float A = -expf(A_log[0]);
    float dt = active ? dtv[r] : 0.f;
    float s = dt;
    #pragma unroll
    for (int m = 1; m <= 32; m <<= 1) {
        float o = __shfl_up(s, m);
        if (lane >= m) s += o;
    }
    if (j == 63) w0sum = s;
    __syncthreads();
    if (j >= 64 && active) s += w0sum;
    if (j == 127) stot = s;
    __syncthreads();
    if (active) {
        float sT = stot;
        sarr[r] = s;
        Pv[r]   = expf(A * s);
        EdTv[r] = expf(A * (sT - s)) * dt;
        if (j == 127) chp[bc] = expf(A * sT);
    }
}

// GEMM1 (XCD-aware swizzle: per-XCD bm band) + fused cumsum (tail blocks)
__global__ __launch_bounds__(256) void gemm1_kernel(
    const bf16_t* __restrict__ xb, const bf16_t* __restrict__ winb,
    bf16_t* __restrict__ zx, const float* __restrict__ dtv,
    const float* __restrict__ A_log, float* __restrict__ sarr,
    float* __restrict__ Pv, float* __restrict__ EdTv, float* __restrict__ chp)
{
    __shared__ __align__(16) unsigned char smem[32768];
    int linear = blockIdx.x;
    if (linear < (NZX / 128) * (MROWS / 128)) {     // 18*64 = 1152
        int xcd = linear & 7, j = linear >> 3;      // j in [0,144)
        int bm = xcd * 8 + (j & 7);                 // 8-row bm band per XCD
        int bn = j >> 3;                            // [0,18)
        gemm_body<bf16_t>(smem, xb, winb, zx, NZX, DMODEL, DMODEL, DMODEL, bn, bm);
    } else {
        cumsum_body(dtv, A_log, sarr, Pv, EdTv, chp, linear - 1152);
    }
}

// GEMM2 with the same XCD-aware swizzle (256 blocks: 4 bn x 64 bm)
__global__ __launch_bounds__(256) void gemm2_kernel(
    const bf16_t* __restrict__ yb, const bf16_t* __restrict__ woutb,
    float* __restrict__ out)
{
    __shared__ __align__(16) unsigned char smem[32768];
    int linear = blockIdx.x;                        // [0,256)
    int xcd = linear & 7, j = linear >> 3;          // j in [0,32)
    int bm = xcd * 8 + (j & 7);
    int bn = j >> 3;                                // [0,4)
    gemm_body<float>(smem, yb, woutb, out, DMODEL, DINNER, DINNER, DINNER, bn, bm);
}

// ---------------------------------------------------------------------------
// mbuild body (smem: 67 KB): stage C,B tiles (swizzled), MFMA G = C@B^T,
// write Mx = [mask-decay(G) | P*C] bf16.
// ---------------------------------------------------------------------------
__device__ __forceinline__ void mbuild_body(
    unsigned char* smem,
    const float* __restrict__ sarr, const float* __restrict__ dtv,
    const float* __restrict__ Pv, const float* __restrict__ A_log,
    const bf16_t* __restrict__ xbc, bf16_t* __restrict__ Mx, int bc)
{
    bf16_t* Cs  = (bf16_t*)smem;
    bf16_t* Bs2 = (bf16_t*)(smem + 32768);
    float* sj = (float*)(smem + 65536);
    float* dj = (float*)(smem + 65536 + 512);
    float* pj = (float*)(smem + 65536 + 1024);

    int tid = threadIdx.x;
    if (tid < CHUNK) {
        sj[tid] = sarr[bc * CHUNK + tid];
        dj[tid] = dtv[bc * CHUNK + tid];
        pj[tid] = Pv[bc * CHUNK + tid];
    }
    int rowbase = bc * 128;
    int srow = tid >> 4;
    int gsw  = (((tid & 15) ^ (srow & 7))) * 8;
    int lsl  = (tid & 15) * 8;
    #pragma unroll
    for (int i = 0; i < 8; ++i) {
        int row = srow + i * 16;
        load_lds16(&xbc[(size_t)(rowbase + row) * NCONV + 1152 + gsw], &Cs[row * 128 + lsl]);
        load_lds16(&xbc[(size_t)(rowbase + row) * NCONV + 1024 + gsw], &Bs2[row * 128 + lsl]);
    }
    __syncthreads();

    const int wave = tid >> 6, lane = tid & 63;
    const int lr = lane & 15, q = lane >> 4;
    const int wm = (wave & 1) * 64, wn = (wave >> 1) * 64;

    f32x4 acc[4][4];
    #pragma unroll
    for (int i = 0; i < 4; ++i)
        #pragma unroll
        for (int j = 0; j < 4; ++j)
            acc[i][j] = (f32x4){0.f, 0.f, 0.f, 0.f};

    #pragma unroll
    for (int k0 = 0; k0 < 128; k0 += 32) {
        bf16x8 af[4], bfr[4];
        #pragma unroll
        for (int mi = 0; mi < 4; ++mi) {
            int r = wm + mi * 16 + lr, kc = (k0 >> 3) + q;
            af[mi] = *reinterpret_cast<const bf16x8*>(
                &Cs[r * 128 + ((kc ^ (r & 7)) << 3)]);
        }
        #pragma unroll
        for (int ni = 0; ni < 4; ++ni) {
            int r = wn + ni * 16 + lr, kc = (k0 >> 3) + q;
            bfr[ni] = *reinterpret_cast<const bf16x8*>(
                &Bs2[r * 128 + ((kc ^ (r & 7)) << 3)]);
        }
        #pragma unroll
        for (int mi = 0; mi < 4; ++mi)
            #pragma unroll
            for (int ni = 0; ni < 4; ++ni)
                acc[mi][ni] = __builtin_amdgcn_mfma_f32_16x16x32_bf16(
                    af[mi], bfr[ni], acc[mi][ni], 0, 0, 0);
    }

    float A = -expf(A_log[0]);
    bf16_t* MxB = Mx + (size_t)bc * 32768;
    #pragma unroll
    for (int mi = 0; mi < 4; ++mi)
        #pragma unroll
        for (int ni = 0; ni < 4; ++ni)
            #pragma unroll
            for (int ri = 0; ri < 4; ++ri) {
                int row = wm + mi * 16 + q * 4 + ri;
                int col = wn + ni * 16 + lr;
                float val = 0.f;
                if (col <= row)
                    val = acc[mi][ni][ri] * expf(A * (sj[row] - sj[col])) * dj[col];
                MxB[(size_t)row * 256 + col] = (bf16_t)val;
            }

    // Cw half from LDS (undo swizzle): Mx[row][128+n] = P_row * C[row][n]
    int rr = tid >> 1, cb2 = (tid & 1) * 64;
    float Pi = pj[rr];
    #pragma unroll
    for (int m0 = 0; m0 < 64; m0 += 8) {
        int kc = (cb2 + m0) >> 3;
        bf16x8 cv = *reinterpret_cast<const bf16x8*>(
            &Cs[rr * 128 + ((kc ^ (rr & 7)) << 3)]);
        bf16x8 o;
        #pragma unroll
        for (int m = 0; m < 8; ++m) o[m] = (bf16_t)((float)cv[m] * Pi);
        *reinterpret_cast<bf16x8*>(&MxB[(size_t)rr * 256 + 128 + cb2 + m0]) = o;
    }
}

// Merged GEMM-A (blocks 0..511) + mbuild (blocks 512..575)
__global__ __launch_bounds__(256) void gemmA_mbuild_kernel(
    const bf16_t* __restrict__ Xt, const bf16_t* __restrict__ Bwt,
    bf16_t* __restrict__ cstate,
    const float* __restrict__ sarr, const float* __restrict__ dtv,
    const float* __restrict__ Pv, const float* __restrict__ A_log,
    const bf16_t* __restrict__ xbc, bf16_t* __restrict__ Mx)
{
    __shared__ __align__(16) unsigned char smem[67072];
    int id = blockIdx.x;
    if (id < 512) {
        int bc = id & 63, bm = id >> 6;             // bm in [0,8)
        gemm_body<bf16_t>(smem,
            Xt + (size_t)bc * 131072, Bwt + (size_t)bc * 16384,
            cstate + (size_t)bc * 131072,
            DSTATE, CHUNK, CHUNK, CHUNK, 0, bm);
    } else {
        mbuild_body(smem, sarr, dtv, Pv, A_log, xbc, Mx, id - 512);
    }
}

// ---------------------------------------------------------------------------
// Y-GEMM: Y[i,p] = sum_{k<256} Mx[i,k] * Dx[p,k]; Dx = [Xt | Stb] per chunk.
// ---------------------------------------------------------------------------
__global__ __launch_bounds__(256) void gemm_y_kernel(
    const bf16_t* __restrict__ Mx, const bf16_t* __restrict__ Xt,
    const bf16_t* __restrict__ Stb, bf16_t* __restrict__ yf)
{
    __shared__ __align__(16) bf16_t As[128 * 64];
    __shared__ __align__(16) bf16_t Bs[128 * 64];

    const int bc = blockIdx.z, bn = blockIdx.x;
    const bf16_t* Ab = Mx + (size_t)bc * 32768;                      // 128x256
    const bf16_t* Xb = Xt  + (size_t)bc * 131072 + (size_t)bn * 128 * 128;
    const bf16_t* Sb = Stb + (size_t)bc * 131072 + (size_t)bn * 128 * 128;
    bf16_t* Cb = yf + (size_t)bc * 131072;

    const int tid  = threadIdx.x;
    const int wave = tid >> 6, lane = tid & 63;
    const int lr = lane & 15, q = lane >> 4;
    const int wm = (wave & 1) * 64, wn = (wave >> 1) * 64;

    f32x4 acc[4][4];
    #pragma unroll
    for (int i = 0; i < 4; ++i)
        #pragma unroll
        for (int j = 0; j < 4; ++j)
            acc[i][j] = (f32x4){0.f, 0.f, 0.f, 0.f};

    const int srow = tid >> 3;
    const int gsw  = (((tid & 7) ^ (srow & 7))) * 8;
    const int lsl  = (tid & 7) * 8;

    for (int kt = 0; kt < 256; kt += 64) {
        const bf16_t* bsrc = (kt < 128) ? (Xb + kt) : (Sb + (kt - 128));
        #pragma unroll
        for (int i = 0; i < 4; ++i) {
            int row = srow + i * 32;
            load_lds16(&Ab[(size_t)row * 256 + kt + gsw], &As[row * 64 + lsl]);
            load_lds16(&bsrc[(size_t)row * 128 + gsw], &Bs[row * 64 + lsl]);
        }
        __syncthreads();
        #pragma unroll
        for (int k0 = 0; k0 < 64; k0 += 32) {
            bf16x8 af[4], bfr[4];
            #pragma unroll
            for (int mi = 0; mi < 4; ++mi) {
                int r = wm + mi * 16 + lr, kc = (k0 >> 3) + q;
                af[mi] = *reinterpret_cast<const bf16x8*>(
                    &As[r * 64 + ((kc ^ (r & 7)) << 3)]);
            }
            #pragma unroll
            for (int ni = 0; ni < 4; ++ni) {
                int r = wn + ni * 16 + lr, kc = (k0 >> 3) + q;
                bfr[ni] = *reinterpret_cast<const bf16x8*>(
                    &Bs[r * 64 + ((kc ^ (r & 7)) << 3)]);
            }
            #pragma unroll
            for (int mi = 0; mi < 4; ++mi)
                #pragma unroll
                for (int ni = 0; ni < 4; ++ni)
                    acc[mi][ni] = __builtin_amdgcn_mfma_f32_16x16x32_bf16(
                        af[mi], bfr[ni], acc[mi][ni], 0, 0, 0);
        }
        __syncthreads();
    }

    #pragma unroll
    for (int mi = 0; mi < 4; ++mi)
        #pragma unroll
        for (int ni = 0; ni < 4; ++ni)
            #pragma unroll
            for (int ri = 0; ri < 4; ++ri) {
                int row = wm + mi * 16 + q * 4 + ri;
                int col = bn * 128 + wn + ni * 16 + lr;
                Cb[(size_t)row * 1024 + col] = (bf16_t)acc[mi][ni][ri];
            }
}

// ---------------------------------------------------------------------------
// Fused: dt column (one wave per row, fp32 exact) + x->bf16 cast  [blocks
// 0..2047], then W_in/W_out -> bf16 casts [blocks 2048..].
// ---------------------------------------------------------------------------
__global__ __launch_bounds__(256) void dtcast_kernel(
    const float* __restrict__ x, const float* __restrict__ W_in,
    const float* __restrict__ dt_bias, const float* __restrict__ W_out,
    float* __restrict__ dtv, bf16_t* __restrict__ xb,
    bf16_t* __restrict__ winb, bf16_t* __restrict__ woutb)
{
    int bid = blockIdx.x;
    if (bid < MROWS / 4) {
        int wave = threadIdx.x >> 6, lane = threadIdx.x & 63;
        int r = bid * 4 + wave;
        const float* xr = x + (size_t)r * DMODEL + lane * 8;
        const float* wr = W_in + (size_t)NZX * DMODEL + lane * 8;
        float4 a0 = *reinterpret_cast<const float4*>(xr);
        float4 a1 = *reinterpret_cast<const float4*>(xr + 4);
        float4 b0 = *reinterpret_cast<const float4*>(wr);
        float4 b1 = *reinterpret_cast<const float4*>(wr + 4);

        bf16x8 xo;
        xo[0] = (bf16_t)a0.x; xo[1] = (bf16_t)a0.y; xo[2] = (bf16_t)a0.z; xo[3] = (bf16_t)a0.w;
        xo[4] = (bf16_t)a1.x; xo[5] = (bf16_t)a1.y; xo[6] = (bf16_t)a1.z; xo[7] = (bf16_t)a1.w;
        *reinterpret_cast<bf16x8*>(xb + (size_t)r * DMODEL + lane * 8) = xo;

        float s = a0.x * b0.x + a0.y * b0.y + a0.z * b0.z + a0.w * b0.w
                + a1.x * b1.x + a1.y * b1.y + a1.z * b1.z + a1.w * b1.w;
        #pragma unroll
        for (int m = 32; m >= 1; m >>= 1) s += __shfl_xor(s, m);
        if (lane == 0) {
            float t  = s + dt_bias[0];
            dtv[r] = (t > 20.f) ? t : log1pf(expf(t));
        }
        return;
    }
    int i = (bid - MROWS / 4) * 256 + threadIdx.x;
    const int n4a = 2305 * DMODEL / 4, n4b = DMODEL * DINNER / 4;
    const float* src; bf16_t* dst; int j;
    if (i < n4a)            { src = W_in;  dst = winb;  j = i; }
    else if (i < n4a + n4b) { src = W_out; dst = woutb; j = i - n4a; }
    else return;
    float4 v = reinterpret_cast<const float4*>(src)[j];
    bf16x4 o;
    o[0] = (bf16_t)v.x; o[1] = (bf16_t)v.y; o[2] = (bf16_t)v.z; o[3] = (bf16_t)v.w;
    reinterpret_cast<bf16x4*>(dst)[j] = o;
}

// ---------------------------------------------------------------------------
// Fused conv + transpose (R11 layout): 1280 blocks, 128x64 tile, TS=66.
// ---------------------------------------------------------------------------
__global__ __launch_bounds__(256) void conv_tr_kernel(
    const bf16_t* __restrict__ zx, const float* __restrict__ cw,
    const float* __restrict__ cb, const float* __restrict__ EdTv,
    bf16_t* __restrict__ xbc, bf16_t* __restrict__ Xt, bf16_t* __restrict__ Bwt)
{
    constexpr int TS = 66;                 // 132B row stride = 33 banks (odd)
    __shared__ bf16_t tile[128 * TS];      // [j][ch_local]
    __shared__ float cwS[64 * 4];
    __shared__ float cbS[64];

    int id  = blockIdx.x;                  // [0,1280)
    int xcd = id & 7;
    int k   = id >> 3;                     // [0,160)
    int bc  = xcd * 8 + (k & 7);           // zx band bc lives in XCD bc>>3 L2
    int rest = k >> 3;                     // [0,20)
    int cg   = rest >> 1;                  // [0,10)
    int half = rest & 1;
    int c0   = cg * 128 + half * 64;       // global channel base in [0,1280)
    int tid  = threadIdx.x;

    if (tid < 64) {
        float4 w = *reinterpret_cast<const float4*>(cw + (size_t)(c0 + tid) * 4);
        *reinterpret_cast<float4*>(&cwS[tid * 4]) = w;
        cbS[tid] = cb[c0 + tid];
    }
    __syncthreads();

    int lrow = tid >> 3;                   // 0..31
    int lc8  = (tid & 7) * 8;              // 0..56 (channel-local)
    int g0 = bc * 128;

    #pragma unroll
    for (int pass = 0; pass < 4; ++pass) {
        int row = pass * 32 + lrow;        // j in chunk
        int g = g0 + row;
        int l = g & (SEQLEN - 1);
        float acc[8];
        #pragma unroll
        for (int m = 0; m < 8; ++m) acc[m] = cbS[lc8 + m];
        #pragma unroll
        for (int kk = 0; kk < 4; ++kk) {
            if (l + kk >= 3) {
                bf16x8 v = *reinterpret_cast<const bf16x8*>(
                    zx + (size_t)(g + kk - 3) * NZX + DINNER + c0 + lc8);
                #pragma unroll
                for (int m = 0; m < 8; ++m)
                    acc[m] += cwS[(lc8 + m) * 4 + kk] * (float)v[m];
            }
        }
        bf16x8 o;
        #pragma unroll
        for (int m = 0; m < 8; ++m) o[m] = (bf16_t)siluf(acc[m]);
        *reinterpret_cast<bf16x8*>(xbc + (size_t)g * NCONV + c0 + lc8) = o;
        if (cg < 9) {
            #pragma unroll
            for (int jj = 0; jj < 4; ++jj) {
                bf16x2 p; p[0] = o[jj * 2]; p[1] = o[jj * 2 + 1];
                *reinterpret_cast<bf16x2*>(&tile[row * TS + lc8 + jj * 2]) = p;
            }
        }
    }
    if (cg == 9) return;
    __syncthreads();

    const bool isB = (cg == 8);
    int jo = (tid >> 4) * 8;               // j-block 0..120
    int i  = tid & 15;
    float sc[8];
    #pragma unroll
    for (int m = 0; m < 8; ++m)
        sc[m] = isB ? EdTv[bc * 128 + jo + m] : 1.f;

    #pragma unroll
    for (int pass = 0; pass < 4; ++pass) {
        int oc = pass * 16 + i;            // channel-local 0..63
        bf16x8 o;
        #pragma unroll
        for (int m = 0; m < 8; ++m)
            o[m] = (bf16_t)((float)tile[(jo + m) * TS + oc] * sc[m]);
        bf16_t* dst = isB
            ? (Bwt + (size_t)bc * 16384 + (size_t)(c0 - 1024 + oc) * 128 + jo)
            : (Xt + (size_t)bc * 131072 + (size_t)(c0 + oc) * 128 + jo);
        *reinterpret_cast<bf16x8*>(dst) = o;
    }
}

// ---------------------------------------------------------------------------
// Sequential chunk combine, prefetch-all: S_init(c) = chp*S_init + S_loc.
// All 16 chunk loads issued up front (independent addresses) -> one
// latency round-trip instead of 16.
// ---------------------------------------------------------------------------
__global__ __launch_bounds__(256) void scan_combine_kernel(
    const bf16_t* __restrict__ cstate, const float* __restrict__ chp,
    bf16_t* __restrict__ Stb)
{
    __shared__ float chS[NCHUNK];
    int idx = blockIdx.x * 256 + threadIdx.x;   // B * 131072
    int b   = idx >> 17;
    int np  = idx & 131071;
    if (threadIdx.x < NCHUNK) chS[threadIdx.x] = chp[b * NCHUNK + threadIdx.x];
    __syncthreads();

    const bf16_t* src = cstate + ((size_t)b << 21) + np;
    bf16_t*       dst = Stb    + ((size_t)b << 21) + np;
    float t[NCHUNK];
    #pragma unroll
    for (int c = 0; c < NCHUNK; ++c) t[c] = (float)src[(size_t)c << 17];
    float v = 0.f;
    #pragma unroll
    for (int c = 0; c < NCHUNK; ++c) {
        dst[(size_t)c << 17] = (bf16_t)v;
        v = chS[c] * v + t[c];
    }
}

// ---------------------------------------------------------------------------
// Gate + RMSNorm, wave-per-row (no LDS, no barrier):
// lane owns cols [lane*8, lane*8+8) and [512+lane*8, 512+lane*8+8).
// Shuffle-only row reduction. Tail blocks: rnn passthrough.
// ---------------------------------------------------------------------------
__global__ __launch_bounds__(256) void gate_norm_kernel(
    const bf16_t* __restrict__ yf, const bf16_t* __restrict__ zx,
    const bf16_t* __restrict__ xbc, const float* __restrict__ Dp,
    const float* __restrict__ norm_w, bf16_t* __restrict__ yb,
    const float* __restrict__ rnn, float* __restrict__ outTail)
{
    int blk = blockIdx.x, tid = threadIdx.x;
    if (blk >= MROWS / 4) {
        int i = (blk - MROWS / 4) * 256 + tid;
        if (i < BATCH * DMODEL) outTail[i] = rnn[i];
        return;
    }
    int wave = tid >> 6, lane = tid & 63;
    int r = blk * 4 + wave;
    int p0 = lane * 8, p1 = 512 + lane * 8;
    float D0 = Dp[0];

    bf16x8 y0 = *reinterpret_cast<const bf16x8*>(yf + (size_t)r * DINNER + p0);
    bf16x8 y1 = *reinterpret_cast<const bf16x8*>(yf + (size_t)r * DINNER + p1);
    bf16x8 z0 = *reinterpret_cast<const bf16x8*>(zx + (size_t)r * NZX + p0);
    bf16x8 z1 = *reinterpret_cast<const bf16x8*>(zx + (size_t)r * NZX + p1);
    bf16x8 x0 = *reinterpret_cast<const bf16x8*>(xbc + (size_t)r * NCONV + p0);
    bf16x8 x1 = *reinterpret_cast<const bf16x8*>(xbc + (size_t)r * NCONV + p1);

    float g[16];
    #pragma unroll
    for (int m = 0; m < 8; ++m) {
        g[m]     = ((float)y0[m] + D0 * (float)x0[m]) * siluf((float)z0[m]);
        g[8 + m] = ((float)y1[m] + D0 * (float)x1[m]) * siluf((float)z1[m]);
    }
    float ss = 0.f;
    #pragma unroll
    for (int m = 0; m < 16; ++m) ss += g[m] * g[m];
    #pragma unroll
    for (int m = 32; m >= 1; m >>= 1) ss += __shfl_xor(ss, m);
    float scale = rsqrtf(ss * (1.f / 1024.f) + 1e-5f);

    const float* nw = norm_w;
    float4 w0a = *reinterpret_cast<const float4*>(nw + p0);
    float4 w0b = *reinterpret_cast<const float4*>(nw + p0 + 4);
    float4 w1a = *reinterpret_cast<const float4*>(nw + p1);
    float4 w1b = *reinterpret_cast<const float4*>(nw + p1 + 4);
    float w[16] = {w0a.x, w0a.y, w0a.z, w0a.w, w0b.x, w0b.y, w0b.z, w0b.w,
                   w1a.x, w1a.y, w1a.z, w1a.w, w1b.x, w1b.y, w1b.z, w1b.w};
    bf16x8 o0, o1;
    #pragma unroll
    for (int m = 0; m < 8; ++m) {
        o0[m] = (bf16_t)(g[m] * scale * w[m]);
        o1[m] = (bf16_t)(g[8 + m] * scale * w[8 + m]);
    }
    *reinterpret_cast<bf16x8*>(yb + (size_t)r * DINNER + p0) = o0;
    *reinterpret_cast<bf16x8*>(yb + (size_t)r * DINNER + p1) = o1;
}

// ---------------------------------------------------------------------------
extern "C" void kernel_launch(void* const* d_in, const int* in_sizes, int n_in,
                              void* d_out, int out_size, void* d_ws, size_t ws_size,
                              hipStream_t stream)
{
    const float* x        = (const float*)d_in[0];
    const float* rnn      = (const float*)d_in[1];
    const float* W_in     = (const float*)d_in[2];
    const float* conv_w   = (const float*)d_in[3];
    const float* conv_b   = (const float*)d_in[4];
    const float* dt_bias  = (const float*)d_in[5];
    const float* A_log    = (const float*)d_in[6];
    const float* Dp       = (const float*)d_in[7];
    const float* norm_w   = (const float*)d_in[8];
    const float* W_out    = (const float*)d_in[9];
    float* out = (float*)d_out;

    // workspace carve
    char* ws = (char*)d_ws;
    bf16_t* xb     = (bf16_t*)(ws + 0);                       //  8,388,608 (dead after GEMM1)
    bf16_t* Mx     = (bf16_t*)(ws + 4194304);                 //  4,194,304 (alias over xb tail)
    bf16_t* winb   = (bf16_t*)(ws + 8388608);                 //  2,360,320
    bf16_t* woutb  = (bf16_t*)(ws + 10748928);                //  1,048,576
    bf16_t* zx     = (bf16_t*)(ws + 11797504);                // 37,748,736
    float*  dtv    = (float*) (ws + 49546240);                //     32,768
    float*  sarr   = (float*) (ws + 49579008);                //     32,768
    float*  Pv     = (float*) (ws + 49611776);                //     32,768
    float*  EdTv   = (float*) (ws + 49644544);                //     32,768
    float*  chp    = (float*) (ws + 49677312);                //        256
    bf16_t* xbcb   = (bf16_t*)(ws + 49677568);                // 20,971,520
    bf16_t* Xt     = (bf16_t*)(ws + 70649088);                // 16,777,216
    bf16_t* Bwt    = (bf16_t*)(ws + 87426304);                //  2,097,152
    bf16_t* cstate = (bf16_t*)(ws + 89523456);                // 16,777,216 (S_loc bf16)
    bf16_t* yf     = (bf16_t*)(ws + 89523456);                // alias over dead cstate
    bf16_t* Stb    = (bf16_t*)(ws + 106300672);               // 16,777,216
    bf16_t* yb     = (bf16_t*)(ws + 123077888);               // 16,777,216
    // end: 139,855,104 bytes

    // 1) dt (fp32) + x cast + weight casts (one kernel, block-range split)
    {
        const int n4a = 2305 * DMODEL / 4, n4b = DMODEL * DINNER / 4;
        int grid = MROWS / 4 + (n4a + n4b + 255) / 256;
        dtcast_kernel<<<grid, 256, 0, stream>>>(
            x, W_in, dt_bias, W_out, dtv, xb, winb, woutb);
    }

    // 2) GEMM1 (XCD-swizzled, + fused cumsum tail blocks)
    gemm1_kernel<<<1152 + NBC, 256, 0, stream>>>(
        xb, winb, zx, dtv, A_log, sarr, Pv, EdTv, chp);

    // 3) fused conv + transpose (1280 blocks, XCD-matched to zx bands)
    conv_tr_kernel<<<1280, 256, 0, stream>>>(
        zx, conv_w, conv_b, EdTv, xbcb, Xt, Bwt);

    // 4) merged GEMM-A (512 blocks) + mbuild (64 blocks)
    gemmA_mbuild_kernel<<<576, 256, 0, stream>>>(
        Xt, Bwt, cstate, sarr, dtv, Pv, A_log, xbcb, Mx);

    // 5) combine -> Stb bf16 (S_init per chunk, [p,n]), prefetch-all
    scan_combine_kernel<<<BATCH * 131072 / 256, 256, 0, stream>>>(cstate, chp, Stb);

    // 6) GEMM-Y: yf[i,p] = Mx @ [Xt;Stb]^T  (bf16 out)
    gemm_y_kernel<<<dim3(8, 1, NBC), 256, 0, stream>>>(Mx, Xt, Stb, yf);

    // 7) gate + RMSNorm, wave-per-row -> yb bf16 (+ rnn passthrough tail)
    gate_norm_kernel<<<MROWS / 4 + 8, 256, 0, stream>>>(
        yf, zx, xbcb, Dp, norm_w, yb, rnn, out + (size_t)MROWS * DMODEL);

    // 8) GEMM2: out[8192,512] = yb @ woutb^T (f32, into d_out, XCD-swizzled)
    gemm2_kernel<<<256, 256, 0, stream>>>(yb, woutb, out);
}

// Round 13
// 208.250 us; speedup vs baseline: 1.1326x; 1.0274x over previous
//
#include <hip/hip_runtime.h>
#include <cstdint>
#include <cstddef>

// ---------------------------------------------------------------------------
// Mamba2 layer forward (B=4, L=2048, d_model=512, d_inner=1024, d_state=128,
// nheads=1, d_conv=4). SSD formulation: scan as chunked bf16 MFMA GEMMs.
// R5 SSD 609->281; R6 global_load_lds 281->263; R7 XOR-swizzle 263->253;
// R8 fusion 253->233; R9 epilogue repack regressed (reverted); R10 XCD
// swizzle; R11 conv_tr odd-bank tile ->219; R12 wave-per-row gate_norm +
// prefetch combine + merged gemmA/mbuild ->214. R13: GEMM2 retiled 64x128
// (512 blocks = 2/CU, was 256 = 1 wave/SIMD with fully-exposed barrier
// latency). 8 launches.
// ---------------------------------------------------------------------------

typedef __bf16 bf16_t;
typedef __bf16 bf16x8 __attribute__((ext_vector_type(8)));
typedef __bf16 bf16x4 __attribute__((ext_vector_type(4)));
typedef __bf16 bf16x2 __attribute__((ext_vector_type(2)));
typedef float  f32x4  __attribute__((ext_vector_type(4)));

#define BATCH   4
#define SEQLEN  2048
#define MROWS   8192
#define DMODEL  512
#define DINNER  1024
#define DSTATE  128
#define NZX     2304
#define NCONV   1280
#define CHUNK   128
#define NCHUNK  16
#define NBC     64            // BATCH * NCHUNK

__device__ __forceinline__ float siluf(float x) { return x / (1.f + __expf(-x)); }

// async global->LDS, 16B per lane. LDS dst is wave-uniform base + lane*16.
__device__ __forceinline__ void load_lds16(const bf16_t* g, bf16_t* l)
{
    __builtin_amdgcn_global_load_lds(
        (const __attribute__((address_space(1))) void*)g,
        (__attribute__((address_space(3))) void*)l,
        16, 0, 0);
}

// ---------------------------------------------------------------------------
// GEMM body (smem: 32 KB): C[m,n] = sum_k A[m*lda+k]*B[n*ldb+k]; 128x128
// tile, BK=64, XOR-swizzled global_load_lds staging, direct-store epilogue.
// ---------------------------------------------------------------------------
template <typename OutT>
__device__ __forceinline__ void gemm_body(
    unsigned char* smem,
    const bf16_t* __restrict__ A, const bf16_t* __restrict__ B,
    OutT* __restrict__ C, int Ntot, int K, int lda, int ldb, int bn, int bm)
{
    bf16_t* As = (bf16_t*)smem;
    bf16_t* Bs = (bf16_t*)(smem + 16384);

    const int tid  = threadIdx.x;
    const int wave = tid >> 6, lane = tid & 63;
    const int lr = lane & 15, q = lane >> 4;
    const int wm = (wave & 1) * 64, wn = (wave >> 1) * 64;

    f32x4 acc[4][4];
    #pragma unroll
    for (int i = 0; i < 4; ++i)
        #pragma unroll
        for (int j = 0; j < 4; ++j)
            acc[i][j] = (f32x4){0.f, 0.f, 0.f, 0.f};

    const int row_a0 = bm * 128, row_b0 = bn * 128;
    const int srow = tid >> 3;
    const int gsw  = (((tid & 7) ^ (srow & 7))) * 8;   // swizzled global chunk
    const int lsl  = (tid & 7) * 8;                    // natural LDS slot

    for (int kt = 0; kt < K; kt += 64) {
        #pragma unroll
        for (int i = 0; i < 4; ++i) {
            int row = srow + i * 32;
            load_lds16(&A[(size_t)(row_a0 + row) * lda + kt + gsw], &As[row * 64 + lsl]);
            load_lds16(&B[(size_t)(row_b0 + row) * ldb + kt + gsw], &Bs[row * 64 + lsl]);
        }
        __syncthreads();
        #pragma unroll
        for (int k0 = 0; k0 < 64; k0 += 32) {
            bf16x8 af[4], bfr[4];
            #pragma unroll
            for (int mi = 0; mi < 4; ++mi) {
                int r = wm + mi * 16 + lr, kc = (k0 >> 3) + q;
                af[mi] = *reinterpret_cast<const bf16x8*>(
                    &As[r * 64 + ((kc ^ (r & 7)) << 3)]);
            }
            #pragma unroll
            for (int ni = 0; ni < 4; ++ni) {
                int r = wn + ni * 16 + lr, kc = (k0 >> 3) + q;
                bfr[ni] = *reinterpret_cast<const bf16x8*>(
                    &Bs[r * 64 + ((kc ^ (r & 7)) << 3)]);
            }
            #pragma unroll
            for (int mi = 0; mi < 4; ++mi)
                #pragma unroll
                for (int ni = 0; ni < 4; ++ni)
                    acc[mi][ni] = __builtin_amdgcn_mfma_f32_16x16x32_bf16(
                        af[mi], bfr[ni], acc[mi][ni], 0, 0, 0);
        }
        __syncthreads();
    }

    #pragma unroll
    for (int mi = 0; mi < 4; ++mi)
        #pragma unroll
        for (int ni = 0; ni < 4; ++ni)
            #pragma unroll
            for (int ri = 0; ri < 4; ++ri) {
                int row = row_a0 + wm + mi * 16 + q * 4 + ri;
                int col = row_b0 + wn + ni * 16 + lr;
                C[(size_t)row * Ntot + col] = (OutT)acc[mi][ni][ri];
            }
}

// ---------------------------------------------------------------------------
// cumsum body (per chunk bc, active threads 0..127): decay scalars.
// ---------------------------------------------------------------------------
__device__ __forceinline__ void cumsum_body(
    const float* __restrict__ dtv, const float* __restrict__ A_log,
    float* __restrict__ sarr, float* __restrict__ Pv,
    float* __restrict__ EdTv, float* __restrict__ chp, int bc)
{
    __shared__ float w0sum, stot;
    int j = threadIdx.x;
    bool active = j < CHUNK;
    int lane = j & 63;
    int r = bc * CHUNK + j;
    float A = -expf(A_log[0]);
    float dt = active ? dtv[r] : 0.f;
    float s = dt;
    #pragma unroll
    for (int m = 1; m <= 32; m <<= 1) {
        float o = __shfl_up(s, m);
        if (lane >= m) s += o;
    }
    if (j == 63) w0sum = s;
    __syncthreads();
    if (j >= 64 && active) s += w0sum;
    if (j == 127) stot = s;
    __syncthreads();
    if (active) {
        float sT = stot;
        sarr[r] = s;
        Pv[r]   = expf(A * s);
        EdTv[r] = expf(A * (sT - s)) * dt;
        if (j == 127) chp[bc] = expf(A * sT);
    }
}

// GEMM1 (XCD-aware swizzle: per-XCD bm band) + fused cumsum (tail blocks)
__global__ __launch_bounds__(256) void gemm1_kernel(
    const bf16_t* __restrict__ xb, const bf16_t* __restrict__ winb,
    bf16_t* __restrict__ zx, const float* __restrict__ dtv,
    const float* __restrict__ A_log, float* __restrict__ sarr,
    float* __restrict__ Pv, float* __restrict__ EdTv, float* __restrict__ chp)
{
    __shared__ __align__(16) unsigned char smem[32768];
    int linear = blockIdx.x;
    if (linear < (NZX / 128) * (MROWS / 128)) {     // 18*64 = 1152
        int xcd = linear & 7, j = linear >> 3;      // j in [0,144)
        int bm = xcd * 8 + (j & 7);                 // 8-row bm band per XCD
        int bn = j >> 3;                            // [0,18)
        gemm_body<bf16_t>(smem, xb, winb, zx, NZX, DMODEL, DMODEL, DMODEL, bn, bm);
    } else {
        cumsum_body(dtv, A_log, sarr, Pv, EdTv, chp, linear - 1152);
    }
}

// ---------------------------------------------------------------------------
// GEMM2, R13: 64x128 tiles, 512 blocks (2/CU), per-wave 32x64 (acc[2][4]).
// out[8192,512] = yb[8192,1024] @ woutb[512,1024]^T, XCD-swizzled.
// ---------------------------------------------------------------------------
__global__ __launch_bounds__(256) void gemm2_kernel(
    const bf16_t* __restrict__ yb, const bf16_t* __restrict__ woutb,
    float* __restrict__ out)
{
    __shared__ __align__(16) bf16_t As[64 * 64];    //  8 KB
    __shared__ __align__(16) bf16_t Bs[128 * 64];   // 16 KB

    int id  = blockIdx.x;              // [0,512)
    int xcd = id & 7, j = id >> 3;     // j in [0,64)
    int bm  = xcd * 16 + (j & 15);     // [0,128): 64-row tiles, XCD bands
    int bn  = j >> 4;                  // [0,4)

    const int tid  = threadIdx.x;
    const int wave = tid >> 6, lane = tid & 63;
    const int lr = lane & 15, q = lane >> 4;
    const int wm = (wave & 1) * 32, wn = (wave >> 1) * 64;

    f32x4 acc[2][4];
    #pragma unroll
    for (int i = 0; i < 2; ++i)
        #pragma unroll
        for (int jj = 0; jj < 4; ++jj)
            acc[i][jj] = (f32x4){0.f, 0.f, 0.f, 0.f};

    const int row_a0 = bm * 64, row_b0 = bn * 128;
    const int srow = tid >> 3;
    const int gsw  = (((tid & 7) ^ (srow & 7))) * 8;
    const int lsl  = (tid & 7) * 8;

    for (int kt = 0; kt < DINNER; kt += 64) {
        #pragma unroll
        for (int i = 0; i < 2; ++i) {
            int row = srow + i * 32;
            load_lds16(&yb[(size_t)(row_a0 + row) * DINNER + kt + gsw], &As[row * 64 + lsl]);
        }
        #pragma unroll
        for (int i = 0; i < 4; ++i) {
            int row = srow + i * 32;
            load_lds16(&woutb[(size_t)(row_b0 + row) * DINNER + kt + gsw], &Bs[row * 64 + lsl]);
        }
        __syncthreads();
        #pragma unroll
        for (int k0 = 0; k0 < 64; k0 += 32) {
            bf16x8 af[2], bfr[4];
            #pragma unroll
            for (int mi = 0; mi < 2; ++mi) {
                int r = wm + mi * 16 + lr, kc = (k0 >> 3) + q;
                af[mi] = *reinterpret_cast<const bf16x8*>(
                    &As[r * 64 + ((kc ^ (r & 7)) << 3)]);
            }
            #pragma unroll
            for (int ni = 0; ni < 4; ++ni) {
                int r = wn + ni * 16 + lr, kc = (k0 >> 3) + q;
                bfr[ni] = *reinterpret_cast<const bf16x8*>(
                    &Bs[r * 64 + ((kc ^ (r & 7)) << 3)]);
            }
            #pragma unroll
            for (int mi = 0; mi < 2; ++mi)
                #pragma unroll
                for (int ni = 0; ni < 4; ++ni)
                    acc[mi][ni] = __builtin_amdgcn_mfma_f32_16x16x32_bf16(
                        af[mi], bfr[ni], acc[mi][ni], 0, 0, 0);
        }
        __syncthreads();
    }

    #pragma unroll
    for (int mi = 0; mi < 2; ++mi)
        #pragma unroll
        for (int ni = 0; ni < 4; ++ni)
            #pragma unroll
            for (int ri = 0; ri < 4; ++ri) {
                int row = row_a0 + wm + mi * 16 + q * 4 + ri;
                int col = row_b0 + wn + ni * 16 + lr;
                out[(size_t)row * DMODEL + col] = acc[mi][ni][ri];
            }
}

// ---------------------------------------------------------------------------
// mbuild body (smem: 67 KB): stage C,B tiles (swizzled), MFMA G = C@B^T,
// write Mx = [mask-decay(G) | P*C] bf16.
// ---------------------------------------------------------------------------
__device__ __forceinline__ void mbuild_body(
    unsigned char* smem,
    const float* __restrict__ sarr, const float* __restrict__ dtv,
    const float* __restrict__ Pv, const float* __restrict__ A_log,
    const bf16_t* __restrict__ xbc, bf16_t* __restrict__ Mx, int bc)
{
    bf16_t* Cs  = (bf16_t*)smem;
    bf16_t* Bs2 = (bf16_t*)(smem + 32768);
    float* sj = (float*)(smem + 65536);
    float* dj = (float*)(smem + 65536 + 512);
    float* pj = (float*)(smem + 65536 + 1024);

    int tid = threadIdx.x;
    if (tid < CHUNK) {
        sj[tid] = sarr[bc * CHUNK + tid];
        dj[tid] = dtv[bc * CHUNK + tid];
        pj[tid] = Pv[bc * CHUNK + tid];
    }
    int rowbase = bc * 128;
    int srow = tid >> 4;
    int gsw  = (((tid & 15) ^ (srow & 7))) * 8;
    int lsl  = (tid & 15) * 8;
    #pragma unroll
    for (int i = 0; i < 8; ++i) {
        int row = srow + i * 16;
        load_lds16(&xbc[(size_t)(rowbase + row) * NCONV + 1152 + gsw], &Cs[row * 128 + lsl]);
        load_lds16(&xbc[(size_t)(rowbase + row) * NCONV + 1024 + gsw], &Bs2[row * 128 + lsl]);
    }
    __syncthreads();

    const int wave = tid >> 6, lane = tid & 63;
    const int lr = lane & 15, q = lane >> 4;
    const int wm = (wave & 1) * 64, wn = (wave >> 1) * 64;

    f32x4 acc[4][4];
    #pragma unroll
    for (int i = 0; i < 4; ++i)
        #pragma unroll
        for (int j = 0; j < 4; ++j)
            acc[i][j] = (f32x4){0.f, 0.f, 0.f, 0.f};

    #pragma unroll
    for (int k0 = 0; k0 < 128; k0 += 32) {
        bf16x8 af[4], bfr[4];
        #pragma unroll
        for (int mi = 0; mi < 4; ++mi) {
            int r = wm + mi * 16 + lr, kc = (k0 >> 3) + q;
            af[mi] = *reinterpret_cast<const bf16x8*>(
                &Cs[r * 128 + ((kc ^ (r & 7)) << 3)]);
        }
        #pragma unroll
        for (int ni = 0; ni < 4; ++ni) {
            int r = wn + ni * 16 + lr, kc = (k0 >> 3) + q;
            bfr[ni] = *reinterpret_cast<const bf16x8*>(
                &Bs2[r * 128 + ((kc ^ (r & 7)) << 3)]);
        }
        #pragma unroll
        for (int mi = 0; mi < 4; ++mi)
            #pragma unroll
            for (int ni = 0; ni < 4; ++ni)
                acc[mi][ni] = __builtin_amdgcn_mfma_f32_16x16x32_bf16(
                    af[mi], bfr[ni], acc[mi][ni], 0, 0, 0);
    }

    float A = -expf(A_log[0]);
    bf16_t* MxB = Mx + (size_t)bc * 32768;
    #pragma unroll
    for (int mi = 0; mi < 4; ++mi)
        #pragma unroll
        for (int ni = 0; ni < 4; ++ni)
            #pragma unroll
            for (int ri = 0; ri < 4; ++ri) {
                int row = wm + mi * 16 + q * 4 + ri;
                int col = wn + ni * 16 + lr;
                float val = 0.f;
                if (col <= row)
                    val = acc[mi][ni][ri] * expf(A * (sj[row] - sj[col])) * dj[col];
                MxB[(size_t)row * 256 + col] = (bf16_t)val;
            }

    // Cw half from LDS (undo swizzle): Mx[row][128+n] = P_row * C[row][n]
    int rr = tid >> 1, cb2 = (tid & 1) * 64;
    float Pi = pj[rr];
    #pragma unroll
    for (int m0 = 0; m0 < 64; m0 += 8) {
        int kc = (cb2 + m0) >> 3;
        bf16x8 cv = *reinterpret_cast<const bf16x8*>(
            &Cs[rr * 128 + ((kc ^ (rr & 7)) << 3)]);
        bf16x8 o;
        #pragma unroll
        for (int m = 0; m < 8; ++m) o[m] = (bf16_t)((float)cv[m] * Pi);
        *reinterpret_cast<bf16x8*>(&MxB[(size_t)rr * 256 + 128 + cb2 + m0]) = o;
    }
}

// Merged GEMM-A (blocks 0..511) + mbuild (blocks 512..575)
__global__ __launch_bounds__(256) void gemmA_mbuild_kernel(
    const bf16_t* __restrict__ Xt, const bf16_t* __restrict__ Bwt,
    bf16_t* __restrict__ cstate,
    const float* __restrict__ sarr, const float* __restrict__ dtv,
    const float* __restrict__ Pv, const float* __restrict__ A_log,
    const bf16_t* __restrict__ xbc, bf16_t* __restrict__ Mx)
{
    __shared__ __align__(16) unsigned char smem[67072];
    int id = blockIdx.x;
    if (id < 512) {
        int bc = id & 63, bm = id >> 6;             // bm in [0,8)
        gemm_body<bf16_t>(smem,
            Xt + (size_t)bc * 131072, Bwt + (size_t)bc * 16384,
            cstate + (size_t)bc * 131072,
            DSTATE, CHUNK, CHUNK, CHUNK, 0, bm);
    } else {
        mbuild_body(smem, sarr, dtv, Pv, A_log, xbc, Mx, id - 512);
    }
}

// ---------------------------------------------------------------------------
// Y-GEMM: Y[i,p] = sum_{k<256} Mx[i,k] * Dx[p,k]; Dx = [Xt | Stb] per chunk.
// ---------------------------------------------------------------------------
__global__ __launch_bounds__(256) void gemm_y_kernel(
    const bf16_t* __restrict__ Mx, const bf16_t* __restrict__ Xt,
    const bf16_t* __restrict__ Stb, bf16_t* __restrict__ yf)
{
    __shared__ __align__(16) bf16_t As[128 * 64];
    __shared__ __align__(16) bf16_t Bs[128 * 64];

    const int bc = blockIdx.z, bn = blockIdx.x;
    const bf16_t* Ab = Mx + (size_t)bc * 32768;                      // 128x256
    const bf16_t* Xb = Xt  + (size_t)bc * 131072 + (size_t)bn * 128 * 128;
    const bf16_t* Sb = Stb + (size_t)bc * 131072 + (size_t)bn * 128 * 128;
    bf16_t* Cb = yf + (size_t)bc * 131072;

    const int tid  = threadIdx.x;
    const int wave = tid >> 6, lane = tid & 63;
    const int lr = lane & 15, q = lane >> 4;
    const int wm = (wave & 1) * 64, wn = (wave >> 1) * 64;

    f32x4 acc[4][4];
    #pragma unroll
    for (int i = 0; i < 4; ++i)
        #pragma unroll
        for (int j = 0; j < 4; ++j)
            acc[i][j] = (f32x4){0.f, 0.f, 0.f, 0.f};

    const int srow = tid >> 3;
    const int gsw  = (((tid & 7) ^ (srow & 7))) * 8;
    const int lsl  = (tid & 7) * 8;

    for (int kt = 0; kt < 256; kt += 64) {
        const bf16_t* bsrc = (kt < 128) ? (Xb + kt) : (Sb + (kt - 128));
        #pragma unroll
        for (int i = 0; i < 4; ++i) {
            int row = srow + i * 32;
            load_lds16(&Ab[(size_t)row * 256 + kt + gsw], &As[row * 64 + lsl]);
            load_lds16(&bsrc[(size_t)row * 128 + gsw], &Bs[row * 64 + lsl]);
        }
        __syncthreads();
        #pragma unroll
        for (int k0 = 0; k0 < 64; k0 += 32) {
            bf16x8 af[4], bfr[4];
            #pragma unroll
            for (int mi = 0; mi < 4; ++mi) {
                int r = wm + mi * 16 + lr, kc = (k0 >> 3) + q;
                af[mi] = *reinterpret_cast<const bf16x8*>(
                    &As[r * 64 + ((kc ^ (r & 7)) << 3)]);
            }
            #pragma unroll
            for (int ni = 0; ni < 4; ++ni) {
                int r = wn + ni * 16 + lr, kc = (k0 >> 3) + q;
                bfr[ni] = *reinterpret_cast<const bf16x8*>(
                    &Bs[r * 64 + ((kc ^ (r & 7)) << 3)]);
            }
            #pragma unroll
            for (int mi = 0; mi < 4; ++mi)
                #pragma unroll
                for (int ni = 0; ni < 4; ++ni)
                    acc[mi][ni] = __builtin_amdgcn_mfma_f32_16x16x32_bf16(
                        af[mi], bfr[ni], acc[mi][ni], 0, 0, 0);
        }
        __syncthreads();
    }

    #pragma unroll
    for (int mi = 0; mi < 4; ++mi)
        #pragma unroll
        for (int ni = 0; ni < 4; ++ni)
            #pragma unroll
            for (int ri = 0; ri < 4; ++ri) {
                int row = wm + mi * 16 + q * 4 + ri;
                int col = bn * 128 + wn + ni * 16 + lr;
                Cb[(size_t)row * 1024 + col] = (bf16_t)acc[mi][ni][ri];
            }
}

// ---------------------------------------------------------------------------
// Fused: dt column (one wave per row, fp32 exact) + x->bf16 cast  [blocks
// 0..2047], then W_in/W_out -> bf16 casts [blocks 2048..].
// ---------------------------------------------------------------------------
__global__ __launch_bounds__(256) void dtcast_kernel(
    const float* __restrict__ x, const float* __restrict__ W_in,
    const float* __restrict__ dt_bias, const float* __restrict__ W_out,
    float* __restrict__ dtv, bf16_t* __restrict__ xb,
    bf16_t* __restrict__ winb, bf16_t* __restrict__ woutb)
{
    int bid = blockIdx.x;
    if (bid < MROWS / 4) {
        int wave = threadIdx.x >> 6, lane = threadIdx.x & 63;
        int r = bid * 4 + wave;
        const float* xr = x + (size_t)r * DMODEL + lane * 8;
        const float* wr = W_in + (size_t)NZX * DMODEL + lane * 8;
        float4 a0 = *reinterpret_cast<const float4*>(xr);
        float4 a1 = *reinterpret_cast<const float4*>(xr + 4);
        float4 b0 = *reinterpret_cast<const float4*>(wr);
        float4 b1 = *reinterpret_cast<const float4*>(wr + 4);

        bf16x8 xo;
        xo[0] = (bf16_t)a0.x; xo[1] = (bf16_t)a0.y; xo[2] = (bf16_t)a0.z; xo[3] = (bf16_t)a0.w;
        xo[4] = (bf16_t)a1.x; xo[5] = (bf16_t)a1.y; xo[6] = (bf16_t)a1.z; xo[7] = (bf16_t)a1.w;
        *reinterpret_cast<bf16x8*>(xb + (size_t)r * DMODEL + lane * 8) = xo;

        float s = a0.x * b0.x + a0.y * b0.y + a0.z * b0.z + a0.w * b0.w
                + a1.x * b1.x + a1.y * b1.y + a1.z * b1.z + a1.w * b1.w;
        #pragma unroll
        for (int m = 32; m >= 1; m >>= 1) s += __shfl_xor(s, m);
        if (lane == 0) {
            float t  = s + dt_bias[0];
            dtv[r] = (t > 20.f) ? t : log1pf(expf(t));
        }
        return;
    }
    int i = (bid - MROWS / 4) * 256 + threadIdx.x;
    const int n4a = 2305 * DMODEL / 4, n4b = DMODEL * DINNER / 4;
    const float* src; bf16_t* dst; int j;
    if (i < n4a)            { src = W_in;  dst = winb;  j = i; }
    else if (i < n4a + n4b) { src = W_out; dst = woutb; j = i - n4a; }
    else return;
    float4 v = reinterpret_cast<const float4*>(src)[j];
    bf16x4 o;
    o[0] = (bf16_t)v.x; o[1] = (bf16_t)v.y; o[2] = (bf16_t)v.z; o[3] = (bf16_t)v.w;
    reinterpret_cast<bf16x4*>(dst)[j] = o;
}

// ---------------------------------------------------------------------------
// Fused conv + transpose (R11 layout): 1280 blocks, 128x64 tile, TS=66.
// ---------------------------------------------------------------------------
__global__ __launch_bounds__(256) void conv_tr_kernel(
    const bf16_t* __restrict__ zx, const float* __restrict__ cw,
    const float* __restrict__ cb, const float* __restrict__ EdTv,
    bf16_t* __restrict__ xbc, bf16_t* __restrict__ Xt, bf16_t* __restrict__ Bwt)
{
    constexpr int TS = 66;                 // 132B row stride = 33 banks (odd)
    __shared__ bf16_t tile[128 * TS];      // [j][ch_local]
    __shared__ float cwS[64 * 4];
    __shared__ float cbS[64];

    int id  = blockIdx.x;                  // [0,1280)
    int xcd = id & 7;
    int k   = id >> 3;                     // [0,160)
    int bc  = xcd * 8 + (k & 7);           // zx band bc lives in XCD bc>>3 L2
    int rest = k >> 3;                     // [0,20)
    int cg   = rest >> 1;                  // [0,10)
    int half = rest & 1;
    int c0   = cg * 128 + half * 64;       // global channel base in [0,1280)
    int tid  = threadIdx.x;

    if (tid < 64) {
        float4 w = *reinterpret_cast<const float4*>(cw + (size_t)(c0 + tid) * 4);
        *reinterpret_cast<float4*>(&cwS[tid * 4]) = w;
        cbS[tid] = cb[c0 + tid];
    }
    __syncthreads();

    int lrow = tid >> 3;                   // 0..31
    int lc8  = (tid & 7) * 8;              // 0..56 (channel-local)
    int g0 = bc * 128;

    #pragma unroll
    for (int pass = 0; pass < 4; ++pass) {
        int row = pass * 32 + lrow;        // j in chunk
        int g = g0 + row;
        int l = g & (SEQLEN - 1);
        float acc[8];
        #pragma unroll
        for (int m = 0; m < 8; ++m) acc[m] = cbS[lc8 + m];
        #pragma unroll
        for (int kk = 0; kk < 4; ++kk) {
            if (l + kk >= 3) {
                bf16x8 v = *reinterpret_cast<const bf16x8*>(
                    zx + (size_t)(g + kk - 3) * NZX + DINNER + c0 + lc8);
                #pragma unroll
                for (int m = 0; m < 8; ++m)
                    acc[m] += cwS[(lc8 + m) * 4 + kk] * (float)v[m];
            }
        }
        bf16x8 o;
        #pragma unroll
        for (int m = 0; m < 8; ++m) o[m] = (bf16_t)siluf(acc[m]);
        *reinterpret_cast<bf16x8*>(xbc + (size_t)g * NCONV + c0 + lc8) = o;
        if (cg < 9) {
            #pragma unroll
            for (int jj = 0; jj < 4; ++jj) {
                bf16x2 p; p[0] = o[jj * 2]; p[1] = o[jj * 2 + 1];
                *reinterpret_cast<bf16x2*>(&tile[row * TS + lc8 + jj * 2]) = p;
            }
        }
    }
    if (cg == 9) return;
    __syncthreads();

    const bool isB = (cg == 8);
    int jo = (tid >> 4) * 8;               // j-block 0..120
    int i  = tid & 15;
    float sc[8];
    #pragma unroll
    for (int m = 0; m < 8; ++m)
        sc[m] = isB ? EdTv[bc * 128 + jo + m] : 1.f;

    #pragma unroll
    for (int pass = 0; pass < 4; ++pass) {
        int oc = pass * 16 + i;            // channel-local 0..63
        bf16x8 o;
        #pragma unroll
        for (int m = 0; m < 8; ++m)
            o[m] = (bf16_t)((float)tile[(jo + m) * TS + oc] * sc[m]);
        bf16_t* dst = isB
            ? (Bwt + (size_t)bc * 16384 + (size_t)(c0 - 1024 + oc) * 128 + jo)
            : (Xt + (size_t)bc * 131072 + (size_t)(c0 + oc) * 128 + jo);
        *reinterpret_cast<bf16x8*>(dst) = o;
    }
}

// ---------------------------------------------------------------------------
// Sequential chunk combine, prefetch-all: S_init(c) = chp*S_init + S_loc.
// ---------------------------------------------------------------------------
__global__ __launch_bounds__(256) void scan_combine_kernel(
    const bf16_t* __restrict__ cstate, const float* __restrict__ chp,
    bf16_t* __restrict__ Stb)
{
    __shared__ float chS[NCHUNK];
    int idx = blockIdx.x * 256 + threadIdx.x;   // B * 131072
    int b   = idx >> 17;
    int np  = idx & 131071;
    if (threadIdx.x < NCHUNK) chS[threadIdx.x] = chp[b * NCHUNK + threadIdx.x];
    __syncthreads();

    const bf16_t* src = cstate + ((size_t)b << 21) + np;
    bf16_t*       dst = Stb    + ((size_t)b << 21) + np;
    float t[NCHUNK];
    #pragma unroll
    for (int c = 0; c < NCHUNK; ++c) t[c] = (float)src[(size_t)c << 17];
    float v = 0.f;
    #pragma unroll
    for (int c = 0; c < NCHUNK; ++c) {
        dst[(size_t)c << 17] = (bf16_t)v;
        v = chS[c] * v + t[c];
    }
}

// ---------------------------------------------------------------------------
// Gate + RMSNorm, wave-per-row (no LDS, no barrier):
// lane owns cols [lane*8, lane*8+8) and [512+lane*8, 512+lane*8+8).
// Shuffle-only row reduction. Tail blocks: rnn passthrough.
// ---------------------------------------------------------------------------
__global__ __launch_bounds__(256) void gate_norm_kernel(
    const bf16_t* __restrict__ yf, const bf16_t* __restrict__ zx,
    const bf16_t* __restrict__ xbc, const float* __restrict__ Dp,
    const float* __restrict__ norm_w, bf16_t* __restrict__ yb,
    const float* __restrict__ rnn, float* __restrict__ outTail)
{
    int blk = blockIdx.x, tid = threadIdx.x;
    if (blk >= MROWS / 4) {
        int i = (blk - MROWS / 4) * 256 + tid;
        if (i < BATCH * DMODEL) outTail[i] = rnn[i];
        return;
    }
    int wave = tid >> 6, lane = tid & 63;
    int r = blk * 4 + wave;
    int p0 = lane * 8, p1 = 512 + lane * 8;
    float D0 = Dp[0];

    bf16x8 y0 = *reinterpret_cast<const bf16x8*>(yf + (size_t)r * DINNER + p0);
    bf16x8 y1 = *reinterpret_cast<const bf16x8*>(yf + (size_t)r * DINNER + p1);
    bf16x8 z0 = *reinterpret_cast<const bf16x8*>(zx + (size_t)r * NZX + p0);
    bf16x8 z1 = *reinterpret_cast<const bf16x8*>(zx + (size_t)r * NZX + p1);
    bf16x8 x0 = *reinterpret_cast<const bf16x8*>(xbc + (size_t)r * NCONV + p0);
    bf16x8 x1 = *reinterpret_cast<const bf16x8*>(xbc + (size_t)r * NCONV + p1);

    float g[16];
    #pragma unroll
    for (int m = 0; m < 8; ++m) {
        g[m]     = ((float)y0[m] + D0 * (float)x0[m]) * siluf((float)z0[m]);
        g[8 + m] = ((float)y1[m] + D0 * (float)x1[m]) * siluf((float)z1[m]);
    }
    float ss = 0.f;
    #pragma unroll
    for (int m = 0; m < 16; ++m) ss += g[m] * g[m];
    #pragma unroll
    for (int m = 32; m >= 1; m >>= 1) ss += __shfl_xor(ss, m);
    float scale = rsqrtf(ss * (1.f / 1024.f) + 1e-5f);

    const float* nw = norm_w;
    float4 w0a = *reinterpret_cast<const float4*>(nw + p0);
    float4 w0b = *reinterpret_cast<const float4*>(nw + p0 + 4);
    float4 w1a = *reinterpret_cast<const float4*>(nw + p1);
    float4 w1b = *reinterpret_cast<const float4*>(nw + p1 + 4);
    float w[16] = {w0a.x, w0a.y, w0a.z, w0a.w, w0b.x, w0b.y, w0b.z, w0b.w,
                   w1a.x, w1a.y, w1a.z, w1a.w, w1b.x, w1b.y, w1b.z, w1b.w};
    bf16x8 o0, o1;
    #pragma unroll
    for (int m = 0; m < 8; ++m) {
        o0[m] = (bf16_t)(g[m] * scale * w[m]);
        o1[m] = (bf16_t)(g[8 + m] * scale * w[8 + m]);
    }
    *reinterpret_cast<bf16x8*>(yb + (size_t)r * DINNER + p0) = o0;
    *reinterpret_cast<bf16x8*>(yb + (size_t)r * DINNER + p1) = o1;
}

// ---------------------------------------------------------------------------
extern "C" void kernel_launch(void* const* d_in, const int* in_sizes, int n_in,
                              void* d_out, int out_size, void* d_ws, size_t ws_size,
                              hipStream_t stream)
{
    const float* x        = (const float*)d_in[0];
    const float* rnn      = (const float*)d_in[1];
    const float* W_in     = (const float*)d_in[2];
    const float* conv_w   = (const float*)d_in[3];
    const float* conv_b   = (const float*)d_in[4];
    const float* dt_bias  = (const float*)d_in[5];
    const float* A_log    = (const float*)d_in[6];
    const float* Dp       = (const float*)d_in[7];
    const float* norm_w   = (const float*)d_in[8];
    const float* W_out    = (const float*)d_in[9];
    float* out = (float*)d_out;

    // workspace carve
    char* ws = (char*)d_ws;
    bf16_t* xb     = (bf16_t*)(ws + 0);                       //  8,388,608 (dead after GEMM1)
    bf16_t* Mx     = (bf16_t*)(ws + 4194304);                 //  4,194,304 (alias over xb tail)
    bf16_t* winb   = (bf16_t*)(ws + 8388608);                 //  2,360,320
    bf16_t* woutb  = (bf16_t*)(ws + 10748928);                //  1,048,576
    bf16_t* zx     = (bf16_t*)(ws + 11797504);                // 37,748,736
    float*  dtv    = (float*) (ws + 49546240);                //     32,768
    float*  sarr   = (float*) (ws + 49579008);                //     32,768
    float*  Pv     = (float*) (ws + 49611776);                //     32,768
    float*  EdTv   = (float*) (ws + 49644544);                //     32,768
    float*  chp    = (float*) (ws + 49677312);                //        256
    bf16_t* xbcb   = (bf16_t*)(ws + 49677568);                // 20,971,520
    bf16_t* Xt     = (bf16_t*)(ws + 70649088);                // 16,777,216
    bf16_t* Bwt    = (bf16_t*)(ws + 87426304);                //  2,097,152
    bf16_t* cstate = (bf16_t*)(ws + 89523456);                // 16,777,216 (S_loc bf16)
    bf16_t* yf     = (bf16_t*)(ws + 89523456);                // alias over dead cstate
    bf16_t* Stb    = (bf16_t*)(ws + 106300672);               // 16,777,216
    bf16_t* yb     = (bf16_t*)(ws + 123077888);               // 16,777,216
    // end: 139,855,104 bytes

    // 1) dt (fp32) + x cast + weight casts (one kernel, block-range split)
    {
        const int n4a = 2305 * DMODEL / 4, n4b = DMODEL * DINNER / 4;
        int grid = MROWS / 4 + (n4a + n4b + 255) / 256;
        dtcast_kernel<<<grid, 256, 0, stream>>>(
            x, W_in, dt_bias, W_out, dtv, xb, winb, woutb);
    }

    // 2) GEMM1 (XCD-swizzled, + fused cumsum tail blocks)
    gemm1_kernel<<<1152 + NBC, 256, 0, stream>>>(
        xb, winb, zx, dtv, A_log, sarr, Pv, EdTv, chp);

    // 3) fused conv + transpose (1280 blocks, XCD-matched to zx bands)
    conv_tr_kernel<<<1280, 256, 0, stream>>>(
        zx, conv_w, conv_b, EdTv, xbcb, Xt, Bwt);

    // 4) merged GEMM-A (512 blocks) + mbuild (64 blocks)
    gemmA_mbuild_kernel<<<576, 256, 0, stream>>>(
        Xt, Bwt, cstate, sarr, dtv, Pv, A_log, xbcb, Mx);

    // 5) combine -> Stb bf16 (S_init per chunk, [p,n]), prefetch-all
    scan_combine_kernel<<<BATCH * 131072 / 256, 256, 0, stream>>>(cstate, chp, Stb);

    // 6) GEMM-Y: yf[i,p] = Mx @ [Xt;Stb]^T  (bf16 out)
    gemm_y_kernel<<<dim3(8, 1, NBC), 256, 0, stream>>>(Mx, Xt, Stb, yf);

    // 7) gate + RMSNorm, wave-per-row -> yb bf16 (+ rnn passthrough tail)
    gate_norm_kernel<<<MROWS / 4 + 8, 256, 0, stream>>>(
        yf, zx, xbcb, Dp, norm_w, yb, rnn, out + (size_t)MROWS * DMODEL);

    // 8) GEMM2 (R13: 64x128 tiles, 512 blocks, XCD-swizzled)
    gemm2_kernel<<<512, 256, 0, stream>>>(yb, woutb, out);
}